// Round 1
// baseline (3442.723 us; speedup 1.0000x reference)
//
#include <hip/hip_runtime.h>
#include <hip/hip_bf16.h>
#include <cstdint>

// Problem constants (b=2, s=4096, dim=1024, heads=64, dim_head=64)
#define M_TOK 8192
#define DIM   1024
#define INNER 4096
#define HEADS 64
#define DH    64
#define QSCALE 0.125f      // 64^-0.5
#define EPS    1e-6f

typedef __hip_bfloat16 bf16;

__device__ __forceinline__ float bfbits2f(unsigned short u) {
  return __uint_as_float(((unsigned)u) << 16);
}
__device__ __forceinline__ unsigned short f2bfbits(float f) {
  __hip_bfloat16 h = __float2bfloat16(f);
  unsigned short u;
  __builtin_memcpy(&u, &h, 2);
  return u;
}

// ---------------------------------------------------------------------------
// GEMM: Y[M,N] = act(X[M,K] @ W[K,N]), X/W fp32, Y bf16.
// Tile: 128(M) x 64(N) x 16(K); 256 threads; 8x4 outputs/thread.
// MODE: 0 = identity (V), 1 = relu (K), 2 = relu*QSCALE (Q)
// ---------------------------------------------------------------------------
template <int MODE>
__global__ __launch_bounds__(256) void gemm_proj(
    const float* __restrict__ X, const float* __restrict__ W,
    bf16* __restrict__ Y, int M, int N, int K)
{
  __shared__ float As[16][132];  // [k][m], pad 132 (row = 528B, 16B-aligned)
  __shared__ float Bs[16][68];   // [k][n]

  const int tid = threadIdx.x;
  const int tx  = tid & 15;      // n direction (x4)
  const int ty  = tid >> 4;      // m direction (x8)
  const int bm  = blockIdx.y * 128;
  const int bn  = blockIdx.x * 64;

  // A loader: rows lr and lr+64, 4 consecutive k's
  const int lr = tid >> 2;
  const int kc = (tid & 3) * 4;
  // B loader: row lbr (k), 4 consecutive n's
  const int lbr = tid >> 4;
  const int lbc = (tid & 15) * 4;

  float acc[8][4];
#pragma unroll
  for (int r = 0; r < 8; ++r)
#pragma unroll
    for (int c = 0; c < 4; ++c) acc[r][c] = 0.f;

  for (int k0 = 0; k0 < K; k0 += 16) {
    const float4 a0 = *reinterpret_cast<const float4*>(&X[(size_t)(bm + lr) * K + k0 + kc]);
    const float4 a1 = *reinterpret_cast<const float4*>(&X[(size_t)(bm + lr + 64) * K + k0 + kc]);
    const float4 b0 = *reinterpret_cast<const float4*>(&W[(size_t)(k0 + lbr) * N + bn + lbc]);
    __syncthreads();
    As[kc + 0][lr] = a0.x; As[kc + 1][lr] = a0.y; As[kc + 2][lr] = a0.z; As[kc + 3][lr] = a0.w;
    As[kc + 0][lr + 64] = a1.x; As[kc + 1][lr + 64] = a1.y;
    As[kc + 2][lr + 64] = a1.z; As[kc + 3][lr + 64] = a1.w;
    *reinterpret_cast<float4*>(&Bs[lbr][lbc]) = b0;
    __syncthreads();
#pragma unroll
    for (int kk = 0; kk < 16; ++kk) {
      const float4 b  = *reinterpret_cast<const float4*>(&Bs[kk][tx * 4]);
      const float4 a0r = *reinterpret_cast<const float4*>(&As[kk][ty * 8]);
      const float4 a1r = *reinterpret_cast<const float4*>(&As[kk][ty * 8 + 4]);
      const float av[8] = {a0r.x, a0r.y, a0r.z, a0r.w, a1r.x, a1r.y, a1r.z, a1r.w};
      const float bv[4] = {b.x, b.y, b.z, b.w};
#pragma unroll
      for (int r = 0; r < 8; ++r)
#pragma unroll
        for (int c = 0; c < 4; ++c) acc[r][c] += av[r] * bv[c];
    }
  }

#pragma unroll
  for (int r = 0; r < 8; ++r) {
    unsigned short us[4];
#pragma unroll
    for (int c = 0; c < 4; ++c) {
      float v = acc[r][c];
      if (MODE >= 1) v = fmaxf(v, 0.f);
      if (MODE == 2) v *= QSCALE;
      us[c] = f2bfbits(v);
    }
    const unsigned int lo = (unsigned)us[0] | ((unsigned)us[1] << 16);
    const unsigned int hi = (unsigned)us[2] | ((unsigned)us[3] << 16);
    uint2 pk; pk.x = lo; pk.y = hi;
    *reinterpret_cast<uint2*>(&Y[(size_t)(bm + ty * 8 + r) * N + bn + tx * 4]) = pk;
  }
}

// ---------------------------------------------------------------------------
// ksum[t][d] = sum_i K[t][i*64+d]  (so V can overwrite K's buffer)
// ---------------------------------------------------------------------------
__global__ __launch_bounds__(64) void ksum_kernel(
    const bf16* __restrict__ Kb, float* __restrict__ ks)
{
  const int t = blockIdx.x;
  const int d = threadIdx.x;
  const unsigned short* row = reinterpret_cast<const unsigned short*>(Kb + (size_t)t * INNER);
  float s = 0.f;
#pragma unroll
  for (int i = 0; i < HEADS; ++i) s += bfbits2f(row[i * DH + d]);
  ks[t * DH + d] = s;
}

// ---------------------------------------------------------------------------
// Per-token attention: A[i*64+j] = sum_d w[i,d]*v[j,d] / (sum_d w[i,d] + eps),
// w[i,d] = q[i,d]*ksum[d].  One block per token. Ab may alias Qb (same-token
// only: all reads of Q land in LDS before any global write).
// ---------------------------------------------------------------------------
__global__ __launch_bounds__(256) void attn_kernel(
    const bf16* __restrict__ Qb, const bf16* __restrict__ Vb,
    const float* __restrict__ ksum, bf16* __restrict__ Ab)
{
  __shared__ float q_s[64][65];  // pad 65: only free 2-way bank aliasing
  __shared__ float v_s[64][65];
  __shared__ float ks_s[64];
  __shared__ float qn_s[64];

  const int t = blockIdx.x;
  const int tid = threadIdx.x;

  const uint4* qsrc = reinterpret_cast<const uint4*>(Qb + (size_t)t * INNER);
  const uint4* vsrc = reinterpret_cast<const uint4*>(Vb + (size_t)t * INNER);
#pragma unroll
  for (int p = 0; p < 2; ++p) {
    const int idx = tid * 2 + p;   // uint4 index, 8 bf16 each
    const int e = idx * 8;
    const int i = e >> 6;
    const int d = e & 63;
    const uint4 uq = qsrc[idx];
    q_s[i][d + 0] = __uint_as_float((uq.x & 0xFFFFu) << 16);
    q_s[i][d + 1] = __uint_as_float(uq.x & 0xFFFF0000u);
    q_s[i][d + 2] = __uint_as_float((uq.y & 0xFFFFu) << 16);
    q_s[i][d + 3] = __uint_as_float(uq.y & 0xFFFF0000u);
    q_s[i][d + 4] = __uint_as_float((uq.z & 0xFFFFu) << 16);
    q_s[i][d + 5] = __uint_as_float(uq.z & 0xFFFF0000u);
    q_s[i][d + 6] = __uint_as_float((uq.w & 0xFFFFu) << 16);
    q_s[i][d + 7] = __uint_as_float(uq.w & 0xFFFF0000u);
    const uint4 uv = vsrc[idx];
    v_s[i][d + 0] = __uint_as_float((uv.x & 0xFFFFu) << 16);
    v_s[i][d + 1] = __uint_as_float(uv.x & 0xFFFF0000u);
    v_s[i][d + 2] = __uint_as_float((uv.y & 0xFFFFu) << 16);
    v_s[i][d + 3] = __uint_as_float(uv.y & 0xFFFF0000u);
    v_s[i][d + 4] = __uint_as_float((uv.z & 0xFFFFu) << 16);
    v_s[i][d + 5] = __uint_as_float(uv.z & 0xFFFF0000u);
    v_s[i][d + 6] = __uint_as_float((uv.w & 0xFFFFu) << 16);
    v_s[i][d + 7] = __uint_as_float(uv.w & 0xFFFF0000u);
  }
  if (tid < 64) ks_s[tid] = ksum[t * 64 + tid];
  __syncthreads();

  // q_s <- w = q * ksum (in place)
  {
    const int i = tid >> 2;
    const int d0 = (tid & 3) * 16;
#pragma unroll
    for (int c = 0; c < 16; ++c) q_s[i][d0 + c] *= ks_s[d0 + c];
  }
  __syncthreads();

  if (tid < 64) {
    float s = 0.f;
#pragma unroll
    for (int d = 0; d < 64; ++d) s += q_s[tid][d];
    qn_s[tid] = s;
  }
  __syncthreads();

  // 4x4 micro-tile of A per thread
  const int i0 = (tid >> 4) * 4;
  const int j0 = (tid & 15) * 4;
  float acc[4][4];
#pragma unroll
  for (int r = 0; r < 4; ++r)
#pragma unroll
    for (int c = 0; c < 4; ++c) acc[r][c] = 0.f;

  for (int d = 0; d < 64; ++d) {
    float qv[4], vv[4];
#pragma unroll
    for (int r = 0; r < 4; ++r) qv[r] = q_s[i0 + r][d];
#pragma unroll
    for (int c = 0; c < 4; ++c) vv[c] = v_s[j0 + c][d];
#pragma unroll
    for (int r = 0; r < 4; ++r)
#pragma unroll
      for (int c = 0; c < 4; ++c) acc[r][c] += qv[r] * vv[c];
  }

  unsigned short* arow = reinterpret_cast<unsigned short*>(Ab + (size_t)t * INNER);
#pragma unroll
  for (int r = 0; r < 4; ++r) {
    const float inv = 1.f / (qn_s[i0 + r] + EPS);
    unsigned short us[4];
#pragma unroll
    for (int c = 0; c < 4; ++c) us[c] = f2bfbits(acc[r][c] * inv);
    uint2 pk;
    pk.x = (unsigned)us[0] | ((unsigned)us[1] << 16);
    pk.y = (unsigned)us[2] | ((unsigned)us[3] << 16);
    *reinterpret_cast<uint2*>(&arow[(i0 + r) * 64 + j0]) = pk;
  }
}

// ---------------------------------------------------------------------------
// out[M,N] = A[M,K](bf16) @ Wo[K,N](fp32) + bo[N], out fp32.
// Same tiling as gemm_proj.
// ---------------------------------------------------------------------------
__global__ __launch_bounds__(256) void gemm_out_k(
    const bf16* __restrict__ A, const float* __restrict__ W,
    const float* __restrict__ bias, float* __restrict__ out,
    int M, int N, int K)
{
  __shared__ float As[16][132];
  __shared__ float Bs[16][68];

  const int tid = threadIdx.x;
  const int tx  = tid & 15;
  const int ty  = tid >> 4;
  const int bm  = blockIdx.y * 128;
  const int bn  = blockIdx.x * 64;

  const int lr = tid >> 2;
  const int kc = (tid & 3) * 4;
  const int lbr = tid >> 4;
  const int lbc = (tid & 15) * 4;

  const unsigned short* Au = reinterpret_cast<const unsigned short*>(A);

  float acc[8][4];
#pragma unroll
  for (int r = 0; r < 8; ++r)
#pragma unroll
    for (int c = 0; c < 4; ++c) acc[r][c] = 0.f;

  for (int k0 = 0; k0 < K; k0 += 16) {
    const ushort4 ua0 = *reinterpret_cast<const ushort4*>(&Au[(size_t)(bm + lr) * K + k0 + kc]);
    const ushort4 ua1 = *reinterpret_cast<const ushort4*>(&Au[(size_t)(bm + lr + 64) * K + k0 + kc]);
    const float4 b0 = *reinterpret_cast<const float4*>(&W[(size_t)(k0 + lbr) * N + bn + lbc]);
    __syncthreads();
    As[kc + 0][lr] = bfbits2f(ua0.x); As[kc + 1][lr] = bfbits2f(ua0.y);
    As[kc + 2][lr] = bfbits2f(ua0.z); As[kc + 3][lr] = bfbits2f(ua0.w);
    As[kc + 0][lr + 64] = bfbits2f(ua1.x); As[kc + 1][lr + 64] = bfbits2f(ua1.y);
    As[kc + 2][lr + 64] = bfbits2f(ua1.z); As[kc + 3][lr + 64] = bfbits2f(ua1.w);
    *reinterpret_cast<float4*>(&Bs[lbr][lbc]) = b0;
    __syncthreads();
#pragma unroll
    for (int kk = 0; kk < 16; ++kk) {
      const float4 b  = *reinterpret_cast<const float4*>(&Bs[kk][tx * 4]);
      const float4 a0r = *reinterpret_cast<const float4*>(&As[kk][ty * 8]);
      const float4 a1r = *reinterpret_cast<const float4*>(&As[kk][ty * 8 + 4]);
      const float av[8] = {a0r.x, a0r.y, a0r.z, a0r.w, a1r.x, a1r.y, a1r.z, a1r.w};
      const float bv[4] = {b.x, b.y, b.z, b.w};
#pragma unroll
      for (int r = 0; r < 8; ++r)
#pragma unroll
        for (int c = 0; c < 4; ++c) acc[r][c] += av[r] * bv[c];
    }
  }

#pragma unroll
  for (int r = 0; r < 8; ++r) {
    float4 v;
    v.x = acc[r][0] + bias[bn + tx * 4 + 0];
    v.y = acc[r][1] + bias[bn + tx * 4 + 1];
    v.z = acc[r][2] + bias[bn + tx * 4 + 2];
    v.w = acc[r][3] + bias[bn + tx * 4 + 3];
    *reinterpret_cast<float4*>(&out[(size_t)(bm + ty * 8 + r) * N + bn + tx * 4]) = v;
  }
}

// ---------------------------------------------------------------------------
// Workspace layout (130 MB total):
//   [0, 64MB)    Q (bf16, 8192x4096) -> later overwritten by A (same-token aliasing)
//   [64, 128MB)  K (bf16) -> after ksum extraction, overwritten by V
//   [128,130MB)  ksum (fp32, 8192x64)
// ---------------------------------------------------------------------------
extern "C" void kernel_launch(void* const* d_in, const int* in_sizes, int n_in,
                              void* d_out, int out_size, void* d_ws, size_t ws_size,
                              hipStream_t stream)
{
  const float* x  = (const float*)d_in[0];
  const float* Wq = (const float*)d_in[1];
  const float* Wk = (const float*)d_in[2];
  const float* Wv = (const float*)d_in[3];
  const float* Wo = (const float*)d_in[4];
  const float* bo = (const float*)d_in[5];
  float* out = (float*)d_out;

  uint8_t* ws = (uint8_t*)d_ws;
  const size_t QK_BYTES = (size_t)M_TOK * INNER * sizeof(bf16);  // 64 MB
  bf16* Qb   = (bf16*)ws;
  bf16* KVb  = (bf16*)(ws + QK_BYTES);
  float* ks  = (float*)(ws + 2 * QK_BYTES);

  dim3 gproj(INNER / 64, M_TOK / 128);  // 64 x 64
  dim3 gout(DIM / 64, M_TOK / 128);     // 16 x 64
  dim3 blk(256);

  // K projection (relu), extract ksum, then V overwrites K's buffer.
  gemm_proj<1><<<gproj, blk, 0, stream>>>(x, Wk, KVb, M_TOK, INNER, DIM);
  ksum_kernel<<<dim3(M_TOK), dim3(64), 0, stream>>>(KVb, ks);
  gemm_proj<0><<<gproj, blk, 0, stream>>>(x, Wv, KVb, M_TOK, INNER, DIM);
  gemm_proj<2><<<gproj, blk, 0, stream>>>(x, Wq, Qb, M_TOK, INNER, DIM);
  attn_kernel<<<dim3(M_TOK), blk, 0, stream>>>(Qb, KVb, ks, Qb /* A aliases Q */);
  gemm_out_k<<<gout, blk, 0, stream>>>(Qb, Wo, bo, out, M_TOK, DIM, INNER);
}

// Round 2
// 627.500 us; speedup vs baseline: 5.4864x; 5.4864x over previous
//
#include <hip/hip_runtime.h>
#include <hip/hip_bf16.h>
#include <cstdint>

// Problem constants (b=2, s=4096, dim=1024, heads=64, dim_head=64)
#define M_TOK 8192
#define DIM   1024
#define INNER 4096
#define HEADS 64
#define DH    64
#define QSCALE 0.125f      // 64^-0.5
#define EPS    1e-6f

typedef __hip_bfloat16 bf16;
typedef __bf16 bf16x8_t __attribute__((ext_vector_type(8)));
typedef float f32x4_t __attribute__((ext_vector_type(4)));

__device__ __forceinline__ float bfbits2f(unsigned short u) {
  return __uint_as_float(((unsigned)u) << 16);
}
__device__ __forceinline__ unsigned short f2bfbits(float f) {
  __hip_bfloat16 h = __float2bfloat16(f);
  unsigned short u;
  __builtin_memcpy(&u, &h, 2);
  return u;
}

// async global->LDS, 16B per lane. LDS dst must be wave-uniform-base + lane*16.
__device__ __forceinline__ void load_lds16(const void* g, void* l) {
  __builtin_amdgcn_global_load_lds(
      (__attribute__((address_space(1))) void*)g,
      (__attribute__((address_space(3))) void*)l, 16, 0, 0);
}

// ---------------------------------------------------------------------------
// cast x (fp32) -> bf16, same layout. One float4 per thread.
// ---------------------------------------------------------------------------
__global__ __launch_bounds__(256) void castx_kernel(
    const float* __restrict__ x, unsigned short* __restrict__ xb, int n4)
{
  const int i = blockIdx.x * 256 + threadIdx.x;
  if (i < n4) {
    const float4 v = reinterpret_cast<const float4*>(x)[i];
    ushort4 o;
    o.x = f2bfbits(v.x); o.y = f2bfbits(v.y);
    o.z = f2bfbits(v.z); o.w = f2bfbits(v.w);
    reinterpret_cast<ushort4*>(xb)[i] = o;
  }
}

// ---------------------------------------------------------------------------
// transpose-cast: W [R][C] fp32 -> Wt [C][R] bf16.  32x32 LDS tiles.
// ---------------------------------------------------------------------------
__global__ __launch_bounds__(256) void tcast_kernel(
    const float* __restrict__ W, unsigned short* __restrict__ Wt, int R, int C)
{
  __shared__ float tile[32][33];
  const int bx = blockIdx.x * 32;   // C offset
  const int by = blockIdx.y * 32;   // R offset
  const int tx = threadIdx.x & 31;
  const int ty = threadIdx.x >> 5;  // 0..7
#pragma unroll
  for (int k = 0; k < 4; ++k)
    tile[ty + k * 8][tx] = W[(size_t)(by + ty + k * 8) * C + bx + tx];
  __syncthreads();
#pragma unroll
  for (int k = 0; k < 4; ++k)
    Wt[(size_t)(bx + ty + k * 8) * R + by + tx] = f2bfbits(tile[tx][ty + k * 8]);
}

// ---------------------------------------------------------------------------
// MFMA GEMM: C[M,N] = act(A[M,K] @ Bt[N,K]^T), all bf16, fp32 accumulate.
// 128x128 tile, BK=32, 256 threads (4 waves, 2x2), 4x4 16x16x32 MFMAs/wave.
// LDS tiles [128][32] bf16, 16B-chunk xor swizzle c' = c ^ ((row>>1)&3):
// keeps global_load_lds lane-contiguity, fragment ds_read_b128 <=2-way banked.
// MODE: 0 = identity (V), 1 = relu (K), 2 = relu*QSCALE (Q)
// ---------------------------------------------------------------------------
template <int MODE>
__global__ __launch_bounds__(256) void gemm_bf16(
    const unsigned short* __restrict__ A,   // [M][K] bf16
    const unsigned short* __restrict__ Bt,  // [N][K] bf16 (B transposed)
    unsigned short* __restrict__ C,         // [M][N] bf16
    int M, int N, int K)
{
  __shared__ __align__(16) unsigned short As[128 * 32];
  __shared__ __align__(16) unsigned short Bs[128 * 32];

  const int tid  = threadIdx.x;
  const int bm   = blockIdx.y * 128;
  const int bn   = blockIdx.x * 128;
  const int lane = tid & 63;
  const int w    = tid >> 6;
  const int wm   = (w & 1) * 64;
  const int wn   = (w >> 1) * 64;
  const int quad = lane >> 4;
  const int l15  = lane & 15;

  f32x4_t acc[4][4];
#pragma unroll
  for (int mt = 0; mt < 4; ++mt)
#pragma unroll
    for (int nt = 0; nt < 4; ++nt) acc[mt][nt] = (f32x4_t){0.f, 0.f, 0.f, 0.f};

  // staging: 512 16B chunks per tile; thread handles chunks tid and tid+256.
  // chunk q -> row = q>>2, stored slot c' = q&3, global chunk c = c' ^ ((row>>1)&3)
  const int q0 = tid, q1 = tid + 256;
  const int row0 = q0 >> 2, row1 = q1 >> 2;
  const int c0 = (q0 & 3) ^ ((q0 >> 3) & 3);
  const int c1 = (q1 & 3) ^ ((q1 >> 3) & 3);

  for (int k0 = 0; k0 < K; k0 += 32) {
    __syncthreads();  // previous iter's LDS reads done before overwrite
    load_lds16(&A [(size_t)(bm + row0) * K + k0 + c0 * 8], &As[q0 * 8]);
    load_lds16(&Bt[(size_t)(bn + row0) * K + k0 + c0 * 8], &Bs[q0 * 8]);
    load_lds16(&A [(size_t)(bm + row1) * K + k0 + c1 * 8], &As[q1 * 8]);
    load_lds16(&Bt[(size_t)(bn + row1) * K + k0 + c1 * 8], &Bs[q1 * 8]);
    __syncthreads();  // implicit s_waitcnt vmcnt(0) drains the lds-DMA

    bf16x8_t af[4], bfr[4];
#pragma unroll
    for (int mt = 0; mt < 4; ++mt) {
      const int r  = wm + mt * 16 + l15;
      const int cp = quad ^ ((r >> 1) & 3);
      af[mt] = *reinterpret_cast<const bf16x8_t*>(&As[r * 32 + cp * 8]);
    }
#pragma unroll
    for (int nt = 0; nt < 4; ++nt) {
      const int r  = wn + nt * 16 + l15;
      const int cp = quad ^ ((r >> 1) & 3);
      bfr[nt] = *reinterpret_cast<const bf16x8_t*>(&Bs[r * 32 + cp * 8]);
    }
#pragma unroll
    for (int mt = 0; mt < 4; ++mt)
#pragma unroll
      for (int nt = 0; nt < 4; ++nt)
        acc[mt][nt] = __builtin_amdgcn_mfma_f32_16x16x32_bf16(
            af[mt], bfr[nt], acc[mt][nt], 0, 0, 0);
  }

  // epilogue: D reg i -> row = quad*4 + i, col = l15 (m89/m91-verified layout)
#pragma unroll
  for (int mt = 0; mt < 4; ++mt)
#pragma unroll
    for (int i = 0; i < 4; ++i) {
      const size_t rowg = (size_t)(bm + wm + mt * 16 + quad * 4 + i);
#pragma unroll
      for (int nt = 0; nt < 4; ++nt) {
        float v = acc[mt][nt][i];
        if (MODE >= 1) v = fmaxf(v, 0.f);
        if (MODE == 2) v *= QSCALE;
        C[rowg * N + bn + wn + nt * 16 + l15] = f2bfbits(v);
      }
    }
}

// ---------------------------------------------------------------------------
// Output MFMA GEMM: out[M,N] = A[M,K] @ Bt[N,K]^T + bias[N], fp32 out.
// ---------------------------------------------------------------------------
__global__ __launch_bounds__(256) void gemm_out_bf16(
    const unsigned short* __restrict__ A,   // [M][K] bf16
    const unsigned short* __restrict__ Bt,  // [N][K] bf16
    const float* __restrict__ bias,
    float* __restrict__ out, int M, int N, int K)
{
  __shared__ __align__(16) unsigned short As[128 * 32];
  __shared__ __align__(16) unsigned short Bs[128 * 32];

  const int tid  = threadIdx.x;
  const int bm   = blockIdx.y * 128;
  const int bn   = blockIdx.x * 128;
  const int lane = tid & 63;
  const int w    = tid >> 6;
  const int wm   = (w & 1) * 64;
  const int wn   = (w >> 1) * 64;
  const int quad = lane >> 4;
  const int l15  = lane & 15;

  f32x4_t acc[4][4];
#pragma unroll
  for (int mt = 0; mt < 4; ++mt)
#pragma unroll
    for (int nt = 0; nt < 4; ++nt) acc[mt][nt] = (f32x4_t){0.f, 0.f, 0.f, 0.f};

  const int q0 = tid, q1 = tid + 256;
  const int row0 = q0 >> 2, row1 = q1 >> 2;
  const int c0 = (q0 & 3) ^ ((q0 >> 3) & 3);
  const int c1 = (q1 & 3) ^ ((q1 >> 3) & 3);

  for (int k0 = 0; k0 < K; k0 += 32) {
    __syncthreads();
    load_lds16(&A [(size_t)(bm + row0) * K + k0 + c0 * 8], &As[q0 * 8]);
    load_lds16(&Bt[(size_t)(bn + row0) * K + k0 + c0 * 8], &Bs[q0 * 8]);
    load_lds16(&A [(size_t)(bm + row1) * K + k0 + c1 * 8], &As[q1 * 8]);
    load_lds16(&Bt[(size_t)(bn + row1) * K + k0 + c1 * 8], &Bs[q1 * 8]);
    __syncthreads();

    bf16x8_t af[4], bfr[4];
#pragma unroll
    for (int mt = 0; mt < 4; ++mt) {
      const int r  = wm + mt * 16 + l15;
      const int cp = quad ^ ((r >> 1) & 3);
      af[mt] = *reinterpret_cast<const bf16x8_t*>(&As[r * 32 + cp * 8]);
    }
#pragma unroll
    for (int nt = 0; nt < 4; ++nt) {
      const int r  = wn + nt * 16 + l15;
      const int cp = quad ^ ((r >> 1) & 3);
      bfr[nt] = *reinterpret_cast<const bf16x8_t*>(&Bs[r * 32 + cp * 8]);
    }
#pragma unroll
    for (int mt = 0; mt < 4; ++mt)
#pragma unroll
      for (int nt = 0; nt < 4; ++nt)
        acc[mt][nt] = __builtin_amdgcn_mfma_f32_16x16x32_bf16(
            af[mt], bfr[nt], acc[mt][nt], 0, 0, 0);
  }

#pragma unroll
  for (int mt = 0; mt < 4; ++mt)
#pragma unroll
    for (int i = 0; i < 4; ++i) {
      const size_t rowg = (size_t)(bm + wm + mt * 16 + quad * 4 + i);
#pragma unroll
      for (int nt = 0; nt < 4; ++nt) {
        const int colg = bn + wn + nt * 16 + l15;
        out[rowg * N + colg] = acc[mt][nt][i] + bias[colg];
      }
    }
}

// ---------------------------------------------------------------------------
// ksum[t][d] = sum_i K[t][i*64+d].  64 threads/token, uint4 loads,
// shfl_xor reduce over the 8 lanes sharing the same d-group.
// ---------------------------------------------------------------------------
__global__ __launch_bounds__(64) void ksum_kernel(
    const unsigned short* __restrict__ Kb, float* __restrict__ ks)
{
  const int t = blockIdx.x;
  const int j = threadIdx.x;  // 0..63
  const uint4* row = reinterpret_cast<const uint4*>(Kb + (size_t)t * INNER);
  float s[8] = {0.f, 0.f, 0.f, 0.f, 0.f, 0.f, 0.f, 0.f};
#pragma unroll
  for (int m = 0; m < 8; ++m) {
    const uint4 u = row[j + 64 * m];   // chunk c = j + 64m: i = c>>3, d0 = (c&7)*8
    s[0] += __uint_as_float((u.x & 0xFFFFu) << 16);
    s[1] += __uint_as_float(u.x & 0xFFFF0000u);
    s[2] += __uint_as_float((u.y & 0xFFFFu) << 16);
    s[3] += __uint_as_float(u.y & 0xFFFF0000u);
    s[4] += __uint_as_float((u.z & 0xFFFFu) << 16);
    s[5] += __uint_as_float(u.z & 0xFFFF0000u);
    s[6] += __uint_as_float((u.w & 0xFFFFu) << 16);
    s[7] += __uint_as_float(u.w & 0xFFFF0000u);
  }
#pragma unroll
  for (int off = 8; off < 64; off <<= 1)
#pragma unroll
    for (int e = 0; e < 8; ++e) s[e] += __shfl_xor(s[e], off, 64);
  if (j < 8) {  // lane j holds d = j*8 .. j*8+7
    float4* dst = reinterpret_cast<float4*>(ks + t * 64 + j * 8);
    float4 lo, hi;
    lo.x = s[0]; lo.y = s[1]; lo.z = s[2]; lo.w = s[3];
    hi.x = s[4]; hi.y = s[5]; hi.z = s[6]; hi.w = s[7];
    dst[0] = lo; dst[1] = hi;
  }
}

// ---------------------------------------------------------------------------
// Per-token attention (unchanged from round 1, verified correct):
// A[i*64+j] = sum_d q[i,d]*ksum[d]*v[j,d] / (sum_d q[i,d]*ksum[d] + eps)
// ---------------------------------------------------------------------------
__global__ __launch_bounds__(256) void attn_kernel(
    const bf16* __restrict__ Qb, const bf16* __restrict__ Vb,
    const float* __restrict__ ksum, bf16* __restrict__ Ab)
{
  __shared__ float q_s[64][65];
  __shared__ float v_s[64][65];
  __shared__ float ks_s[64];
  __shared__ float qn_s[64];

  const int t = blockIdx.x;
  const int tid = threadIdx.x;

  const uint4* qsrc = reinterpret_cast<const uint4*>(Qb + (size_t)t * INNER);
  const uint4* vsrc = reinterpret_cast<const uint4*>(Vb + (size_t)t * INNER);
#pragma unroll
  for (int p = 0; p < 2; ++p) {
    const int idx = tid * 2 + p;
    const int e = idx * 8;
    const int i = e >> 6;
    const int d = e & 63;
    const uint4 uq = qsrc[idx];
    q_s[i][d + 0] = __uint_as_float((uq.x & 0xFFFFu) << 16);
    q_s[i][d + 1] = __uint_as_float(uq.x & 0xFFFF0000u);
    q_s[i][d + 2] = __uint_as_float((uq.y & 0xFFFFu) << 16);
    q_s[i][d + 3] = __uint_as_float(uq.y & 0xFFFF0000u);
    q_s[i][d + 4] = __uint_as_float((uq.z & 0xFFFFu) << 16);
    q_s[i][d + 5] = __uint_as_float(uq.z & 0xFFFF0000u);
    q_s[i][d + 6] = __uint_as_float((uq.w & 0xFFFFu) << 16);
    q_s[i][d + 7] = __uint_as_float(uq.w & 0xFFFF0000u);
    const uint4 uv = vsrc[idx];
    v_s[i][d + 0] = __uint_as_float((uv.x & 0xFFFFu) << 16);
    v_s[i][d + 1] = __uint_as_float(uv.x & 0xFFFF0000u);
    v_s[i][d + 2] = __uint_as_float((uv.y & 0xFFFFu) << 16);
    v_s[i][d + 3] = __uint_as_float(uv.y & 0xFFFF0000u);
    v_s[i][d + 4] = __uint_as_float((uv.z & 0xFFFFu) << 16);
    v_s[i][d + 5] = __uint_as_float(uv.z & 0xFFFF0000u);
    v_s[i][d + 6] = __uint_as_float((uv.w & 0xFFFFu) << 16);
    v_s[i][d + 7] = __uint_as_float(uv.w & 0xFFFF0000u);
  }
  if (tid < 64) ks_s[tid] = ksum[t * 64 + tid];
  __syncthreads();

  {
    const int i = tid >> 2;
    const int d0 = (tid & 3) * 16;
#pragma unroll
    for (int c = 0; c < 16; ++c) q_s[i][d0 + c] *= ks_s[d0 + c];
  }
  __syncthreads();

  if (tid < 64) {
    float s = 0.f;
#pragma unroll
    for (int d = 0; d < 64; ++d) s += q_s[tid][d];
    qn_s[tid] = s;
  }
  __syncthreads();

  const int i0 = (tid >> 4) * 4;
  const int j0 = (tid & 15) * 4;
  float acc[4][4];
#pragma unroll
  for (int r = 0; r < 4; ++r)
#pragma unroll
    for (int c = 0; c < 4; ++c) acc[r][c] = 0.f;

  for (int d = 0; d < 64; ++d) {
    float qv[4], vv[4];
#pragma unroll
    for (int r = 0; r < 4; ++r) qv[r] = q_s[i0 + r][d];
#pragma unroll
    for (int c = 0; c < 4; ++c) vv[c] = v_s[j0 + c][d];
#pragma unroll
    for (int r = 0; r < 4; ++r)
#pragma unroll
      for (int c = 0; c < 4; ++c) acc[r][c] += qv[r] * vv[c];
  }

  unsigned short* arow = reinterpret_cast<unsigned short*>(Ab + (size_t)t * INNER);
#pragma unroll
  for (int r = 0; r < 4; ++r) {
    const float inv = 1.f / (qn_s[i0 + r] + EPS);
    unsigned short us[4];
#pragma unroll
    for (int c = 0; c < 4; ++c) us[c] = f2bfbits(acc[r][c] * inv);
    uint2 pk;
    pk.x = (unsigned)us[0] | ((unsigned)us[1] << 16);
    pk.y = (unsigned)us[2] | ((unsigned)us[3] << 16);
    *reinterpret_cast<uint2*>(&arow[(i0 + r) * 64 + j0]) = pk;
  }
}

// ---------------------------------------------------------------------------
// Buffers:
//  ws   @0      : Q (bf16 8192x4096, 64MB) -> A (attn writes in place)
//  ws   @64MB   : K -> V (bf16, 64MB); first 8MB reused for Wo^T after attn
//  ws   @128MB  : ksum (fp32 8192x64, 2MB)          (total ws = 130MB, as R1)
//  d_out@0      : Xb (bf16 8192x1024, 16MB)  — dead before gemm_out writes
//  d_out@16MB   : Wt (bf16 4096x1024, 8MB) for Wk/Wv/Wq — dead before gemm_out
// ---------------------------------------------------------------------------
extern "C" void kernel_launch(void* const* d_in, const int* in_sizes, int n_in,
                              void* d_out, int out_size, void* d_ws, size_t ws_size,
                              hipStream_t stream)
{
  const float* x  = (const float*)d_in[0];
  const float* Wq = (const float*)d_in[1];
  const float* Wk = (const float*)d_in[2];
  const float* Wv = (const float*)d_in[3];
  const float* Wo = (const float*)d_in[4];
  const float* bo = (const float*)d_in[5];
  float* out = (float*)d_out;

  uint8_t* ws = (uint8_t*)d_ws;
  const size_t QK_BYTES = (size_t)M_TOK * INNER * sizeof(bf16);  // 64 MB
  unsigned short* Qb  = (unsigned short*)ws;                      // Q then A
  unsigned short* KVb = (unsigned short*)(ws + QK_BYTES);         // K then V; then Wo^T
  float* ks           = (float*)(ws + 2 * QK_BYTES);

  unsigned short* Xb = (unsigned short*)d_out;                          // 16 MB
  unsigned short* Wt = (unsigned short*)((uint8_t*)d_out + (16u << 20)); // 8 MB
  unsigned short* Wot = KVb;  // Wo^T over dead V (after attn)

  const dim3 blk(256);
  const dim3 gproj(INNER / 128, M_TOK / 128);  // 32 x 64
  const dim3 gout(DIM / 128, M_TOK / 128);     // 8 x 64
  const dim3 gtc(INNER / 32, DIM / 32);        // W [1024][4096] -> [4096][1024]
  const dim3 gtco(DIM / 32, INNER / 32);       // Wo [4096][1024] -> [1024][4096]

  castx_kernel<<<dim3((M_TOK * DIM / 4 + 255) / 256), blk, 0, stream>>>(
      x, Xb, M_TOK * DIM / 4);

  tcast_kernel<<<gtc, blk, 0, stream>>>(Wk, Wt, DIM, INNER);
  gemm_bf16<1><<<gproj, blk, 0, stream>>>(Xb, Wt, KVb, M_TOK, INNER, DIM);  // K
  ksum_kernel<<<dim3(M_TOK), dim3(64), 0, stream>>>(KVb, ks);

  tcast_kernel<<<gtc, blk, 0, stream>>>(Wv, Wt, DIM, INNER);
  gemm_bf16<0><<<gproj, blk, 0, stream>>>(Xb, Wt, KVb, M_TOK, INNER, DIM);  // V

  tcast_kernel<<<gtc, blk, 0, stream>>>(Wq, Wt, DIM, INNER);
  gemm_bf16<2><<<gproj, blk, 0, stream>>>(Xb, Wt, Qb, M_TOK, INNER, DIM);   // Q

  attn_kernel<<<dim3(M_TOK), blk, 0, stream>>>(
      (const bf16*)Qb, (const bf16*)KVb, ks, (bf16*)Qb);  // A aliases Q

  tcast_kernel<<<gtco, blk, 0, stream>>>(Wo, Wot, INNER, DIM);
  gemm_out_bf16<<<gout, blk, 0, stream>>>(Qb, Wot, bo, out, M_TOK, DIM, INNER);
}

// Round 3
// 563.169 us; speedup vs baseline: 6.1131x; 1.1142x over previous
//
#include <hip/hip_runtime.h>
#include <hip/hip_bf16.h>
#include <cstdint>

// Problem constants (b=2, s=4096, dim=1024, heads=64, dim_head=64)
#define M_TOK 8192
#define DIM   1024
#define INNER 4096
#define HEADS 64
#define DH    64
#define QSCALE 0.125f      // 64^-0.5
#define EPS    1e-6f

typedef __hip_bfloat16 bf16;
typedef __bf16 bf16x8_t __attribute__((ext_vector_type(8)));
typedef float f32x4_t __attribute__((ext_vector_type(4)));

__device__ __forceinline__ float bfbits2f(unsigned short u) {
  return __uint_as_float(((unsigned)u) << 16);
}
__device__ __forceinline__ unsigned short f2bfbits(float f) {
  __hip_bfloat16 h = __float2bfloat16(f);
  unsigned short u;
  __builtin_memcpy(&u, &h, 2);
  return u;
}

// async global->LDS, 16B per lane. LDS dst must be wave-uniform-base + lane*16.
__device__ __forceinline__ void load_lds16(const void* g, void* l) {
  __builtin_amdgcn_global_load_lds(
      (__attribute__((address_space(1))) void*)g,
      (__attribute__((address_space(3))) void*)l, 16, 0, 0);
}

// XCD-aware block swizzle: XCD x owns M-tiles [x*gy/8, (x+1)*gy/8), N-major
// within the XCD so consecutive same-XCD blocks share A-tiles in its L2.
__device__ __forceinline__ void swizzle_xy(int& bx, int& by) {
  const int gx = gridDim.x, gy = gridDim.y;
  const int id  = blockIdx.x + gx * blockIdx.y;
  const int per = gy >> 3;          // M-tiles per XCD (gy % 8 == 0)
  const int xcd = id & 7;
  const int s   = id >> 3;
  by = xcd * per + (s % per);
  bx = s / per;
}

// ---------------------------------------------------------------------------
// cast x (fp32) -> bf16, same layout. One float4 per thread.
// ---------------------------------------------------------------------------
__global__ __launch_bounds__(256) void castx_kernel(
    const float* __restrict__ x, unsigned short* __restrict__ xb, int n4)
{
  const int i = blockIdx.x * 256 + threadIdx.x;
  if (i < n4) {
    const float4 v = reinterpret_cast<const float4*>(x)[i];
    ushort4 o;
    o.x = f2bfbits(v.x); o.y = f2bfbits(v.y);
    o.z = f2bfbits(v.z); o.w = f2bfbits(v.w);
    reinterpret_cast<ushort4*>(xb)[i] = o;
  }
}

// ---------------------------------------------------------------------------
// transpose-cast: W [R][C] fp32 -> Wt [C][R] bf16.  32x32 LDS tiles.
// ---------------------------------------------------------------------------
__global__ __launch_bounds__(256) void tcast_kernel(
    const float* __restrict__ W, unsigned short* __restrict__ Wt, int R, int C)
{
  __shared__ float tile[32][33];
  const int bx = blockIdx.x * 32;   // C offset
  const int by = blockIdx.y * 32;   // R offset
  const int tx = threadIdx.x & 31;
  const int ty = threadIdx.x >> 5;  // 0..7
#pragma unroll
  for (int k = 0; k < 4; ++k)
    tile[ty + k * 8][tx] = W[(size_t)(by + ty + k * 8) * C + bx + tx];
  __syncthreads();
#pragma unroll
  for (int k = 0; k < 4; ++k)
    Wt[(size_t)(bx + ty + k * 8) * R + by + tx] = f2bfbits(tile[tx][ty + k * 8]);
}

// ---------------------------------------------------------------------------
// MFMA GEMM: C[M,N] = act(A[M,K] @ Bt[N,K]^T), all bf16, fp32 accumulate.
// 128x128 tile, BK=32, 256 threads (4 waves, 2x2), 4x4 16x16x32 MFMAs/wave.
// LDS tiles [128][32] bf16, 16B-chunk xor swizzle c' = c ^ ((row>>1)&3).
// MODE: 0 = identity (V), 1 = relu (K), 2 = relu*QSCALE (Q)
// ---------------------------------------------------------------------------
template <int MODE>
__global__ __launch_bounds__(256) void gemm_bf16(
    const unsigned short* __restrict__ A,   // [M][K] bf16
    const unsigned short* __restrict__ Bt,  // [N][K] bf16 (B transposed)
    unsigned short* __restrict__ C,         // [M][N] bf16
    int M, int N, int K)
{
  __shared__ __align__(16) unsigned short As[128 * 32];
  __shared__ __align__(16) unsigned short Bs[128 * 32];

  int bxi, byi;
  swizzle_xy(bxi, byi);
  const int tid  = threadIdx.x;
  const int bm   = byi * 128;
  const int bn   = bxi * 128;
  const int lane = tid & 63;
  const int w    = tid >> 6;
  const int wm   = (w & 1) * 64;
  const int wn   = (w >> 1) * 64;
  const int quad = lane >> 4;
  const int l15  = lane & 15;

  f32x4_t acc[4][4];
#pragma unroll
  for (int mt = 0; mt < 4; ++mt)
#pragma unroll
    for (int nt = 0; nt < 4; ++nt) acc[mt][nt] = (f32x4_t){0.f, 0.f, 0.f, 0.f};

  const int q0 = tid, q1 = tid + 256;
  const int row0 = q0 >> 2, row1 = q1 >> 2;
  const int c0 = (q0 & 3) ^ ((q0 >> 3) & 3);
  const int c1 = (q1 & 3) ^ ((q1 >> 3) & 3);

  for (int k0 = 0; k0 < K; k0 += 32) {
    __syncthreads();
    load_lds16(&A [(size_t)(bm + row0) * K + k0 + c0 * 8], &As[q0 * 8]);
    load_lds16(&Bt[(size_t)(bn + row0) * K + k0 + c0 * 8], &Bs[q0 * 8]);
    load_lds16(&A [(size_t)(bm + row1) * K + k0 + c1 * 8], &As[q1 * 8]);
    load_lds16(&Bt[(size_t)(bn + row1) * K + k0 + c1 * 8], &Bs[q1 * 8]);
    __syncthreads();

    bf16x8_t af[4], bfr[4];
#pragma unroll
    for (int mt = 0; mt < 4; ++mt) {
      const int r  = wm + mt * 16 + l15;
      const int cp = quad ^ ((r >> 1) & 3);
      af[mt] = *reinterpret_cast<const bf16x8_t*>(&As[r * 32 + cp * 8]);
    }
#pragma unroll
    for (int nt = 0; nt < 4; ++nt) {
      const int r  = wn + nt * 16 + l15;
      const int cp = quad ^ ((r >> 1) & 3);
      bfr[nt] = *reinterpret_cast<const bf16x8_t*>(&Bs[r * 32 + cp * 8]);
    }
#pragma unroll
    for (int mt = 0; mt < 4; ++mt)
#pragma unroll
      for (int nt = 0; nt < 4; ++nt)
        acc[mt][nt] = __builtin_amdgcn_mfma_f32_16x16x32_bf16(
            af[mt], bfr[nt], acc[mt][nt], 0, 0, 0);
  }

  // epilogue: D reg i -> row = quad*4 + i, col = l15
#pragma unroll
  for (int mt = 0; mt < 4; ++mt)
#pragma unroll
    for (int i = 0; i < 4; ++i) {
      const size_t rowg = (size_t)(bm + wm + mt * 16 + quad * 4 + i);
#pragma unroll
      for (int nt = 0; nt < 4; ++nt) {
        float v = acc[mt][nt][i];
        if (MODE >= 1) v = fmaxf(v, 0.f);
        if (MODE == 2) v *= QSCALE;
        C[rowg * N + bn + wn + nt * 16 + l15] = f2bfbits(v);
      }
    }
}

// ---------------------------------------------------------------------------
// Output MFMA GEMM: out[M,N] = A[M,K] @ Bt[N,K]^T + bias[N], fp32 out.
// 128(M) x 64(N) tile -> grid (16,64)=1024 blocks = 4 blocks/CU (was 2).
// 4 waves 2x2; wave tile 64x32 (mt=4, nt=2).
// ---------------------------------------------------------------------------
__global__ __launch_bounds__(256) void gemm_out_bf16(
    const unsigned short* __restrict__ A,   // [M][K] bf16
    const unsigned short* __restrict__ Bt,  // [N][K] bf16
    const float* __restrict__ bias,
    float* __restrict__ out, int M, int N, int K)
{
  __shared__ __align__(16) unsigned short As[128 * 32];
  __shared__ __align__(16) unsigned short Bs[64 * 32];

  int bxi, byi;
  swizzle_xy(bxi, byi);
  const int tid  = threadIdx.x;
  const int bm   = byi * 128;
  const int bn   = bxi * 64;
  const int lane = tid & 63;
  const int w    = tid >> 6;
  const int wm   = (w & 1) * 64;
  const int wn   = (w >> 1) * 32;
  const int quad = lane >> 4;
  const int l15  = lane & 15;

  f32x4_t acc[4][2];
#pragma unroll
  for (int mt = 0; mt < 4; ++mt)
#pragma unroll
    for (int nt = 0; nt < 2; ++nt) acc[mt][nt] = (f32x4_t){0.f, 0.f, 0.f, 0.f};

  // A: 512 chunks (2/thread); B: 256 chunks (1/thread)
  const int qa0 = tid, qa1 = tid + 256, qb = tid;
  const int ra0 = qa0 >> 2, ra1 = qa1 >> 2, rb = qb >> 2;
  const int ca0 = (qa0 & 3) ^ ((qa0 >> 3) & 3);
  const int ca1 = (qa1 & 3) ^ ((qa1 >> 3) & 3);
  const int cb  = (qb  & 3) ^ ((qb  >> 3) & 3);

  for (int k0 = 0; k0 < K; k0 += 32) {
    __syncthreads();
    load_lds16(&A [(size_t)(bm + ra0) * K + k0 + ca0 * 8], &As[qa0 * 8]);
    load_lds16(&A [(size_t)(bm + ra1) * K + k0 + ca1 * 8], &As[qa1 * 8]);
    load_lds16(&Bt[(size_t)(bn + rb ) * K + k0 + cb  * 8], &Bs[qb  * 8]);
    __syncthreads();

    bf16x8_t af[4], bfr[2];
#pragma unroll
    for (int mt = 0; mt < 4; ++mt) {
      const int r  = wm + mt * 16 + l15;
      const int cp = quad ^ ((r >> 1) & 3);
      af[mt] = *reinterpret_cast<const bf16x8_t*>(&As[r * 32 + cp * 8]);
    }
#pragma unroll
    for (int nt = 0; nt < 2; ++nt) {
      const int r  = wn + nt * 16 + l15;
      const int cp = quad ^ ((r >> 1) & 3);
      bfr[nt] = *reinterpret_cast<const bf16x8_t*>(&Bs[r * 32 + cp * 8]);
    }
#pragma unroll
    for (int mt = 0; mt < 4; ++mt)
#pragma unroll
      for (int nt = 0; nt < 2; ++nt)
        acc[mt][nt] = __builtin_amdgcn_mfma_f32_16x16x32_bf16(
            af[mt], bfr[nt], acc[mt][nt], 0, 0, 0);
  }

#pragma unroll
  for (int mt = 0; mt < 4; ++mt)
#pragma unroll
    for (int i = 0; i < 4; ++i) {
      const size_t rowg = (size_t)(bm + wm + mt * 16 + quad * 4 + i);
#pragma unroll
      for (int nt = 0; nt < 2; ++nt) {
        const int colg = bn + wn + nt * 16 + l15;
        out[rowg * N + colg] = acc[mt][nt][i] + bias[colg];
      }
    }
}

// ---------------------------------------------------------------------------
// ksum[t][d] = sum_i K[t][i*64+d].  One wave per token, 4 tokens/block.
// ---------------------------------------------------------------------------
__global__ __launch_bounds__(256) void ksum_kernel(
    const unsigned short* __restrict__ Kb, float* __restrict__ ks)
{
  const int t = blockIdx.x * 4 + (threadIdx.x >> 6);
  const int j = threadIdx.x & 63;
  const uint4* row = reinterpret_cast<const uint4*>(Kb + (size_t)t * INNER);
  float s[8] = {0.f, 0.f, 0.f, 0.f, 0.f, 0.f, 0.f, 0.f};
#pragma unroll
  for (int m = 0; m < 8; ++m) {
    const uint4 u = row[j + 64 * m];   // chunk c = j + 64m: i = c>>3, d0 = (c&7)*8
    s[0] += __uint_as_float((u.x & 0xFFFFu) << 16);
    s[1] += __uint_as_float(u.x & 0xFFFF0000u);
    s[2] += __uint_as_float((u.y & 0xFFFFu) << 16);
    s[3] += __uint_as_float(u.y & 0xFFFF0000u);
    s[4] += __uint_as_float((u.z & 0xFFFFu) << 16);
    s[5] += __uint_as_float(u.z & 0xFFFF0000u);
    s[6] += __uint_as_float((u.w & 0xFFFFu) << 16);
    s[7] += __uint_as_float(u.w & 0xFFFF0000u);
  }
#pragma unroll
  for (int off = 8; off < 64; off <<= 1)
#pragma unroll
    for (int e = 0; e < 8; ++e) s[e] += __shfl_xor(s[e], off, 64);
  if (j < 8) {  // lane j holds d = j*8 .. j*8+7
    float4* dst = reinterpret_cast<float4*>(ks + t * 64 + j * 8);
    float4 lo, hi;
    lo.x = s[0]; lo.y = s[1]; lo.z = s[2]; lo.w = s[3];
    hi.x = s[4]; hi.y = s[5]; hi.z = s[6]; hi.w = s[7];
    dst[0] = lo; dst[1] = hi;
  }
}

// ---------------------------------------------------------------------------
// MFMA attention: one wave per token, 4 tokens/block, zero LDS.
//   A_num = Q . diag(ks) . V^T  (ks folded into V, bf16-rounded)
//   qn[i] = sum_d q[i,d]*ks[d]  (in-register + shfl_xor reduce)
//   A[i*64+j] = A_num[i][j] / (qn[i]+eps)
// Fragment layouts identical to the verified GEMM path:
//   A-op: row m = l15, k = quad*8+j ; B-op: row n = l15, k = quad*8+j
//   C/D : col = l15, row = quad*4 + reg
// Ab may alias Qb: wave reads all its Q before any store (per-wave vmcnt order),
// and waves never touch another token's memory.
// ---------------------------------------------------------------------------
__global__ __launch_bounds__(256) void attn_mfma(
    const unsigned short* __restrict__ Qb, const unsigned short* __restrict__ Vb,
    const float* __restrict__ ksum, unsigned short* __restrict__ Ab)
{
  const int t    = blockIdx.x * 4 + (threadIdx.x >> 6);
  const int lane = threadIdx.x & 63;
  const int l15  = lane & 15;
  const int quad = lane >> 4;
  const size_t base = (size_t)t * INNER;

  union VU { bf16x8_t v; unsigned short u[8]; };

  // ks for this lane's k positions: d = kt*32 + quad*8 + j
  float ksv[2][8];
#pragma unroll
  for (int kt = 0; kt < 2; ++kt) {
    const float4* p = reinterpret_cast<const float4*>(ksum + t * 64 + kt * 32 + quad * 8);
    const float4 a = p[0], b = p[1];
    ksv[kt][0] = a.x; ksv[kt][1] = a.y; ksv[kt][2] = a.z; ksv[kt][3] = a.w;
    ksv[kt][4] = b.x; ksv[kt][5] = b.y; ksv[kt][6] = b.z; ksv[kt][7] = b.w;
  }

  // V fragments, scaled by ks then re-rounded to bf16
  bf16x8_t vs[4][2];
#pragma unroll
  for (int nt = 0; nt < 4; ++nt)
#pragma unroll
    for (int kt = 0; kt < 2; ++kt) {
      VU vr, vo;
      vr.v = *reinterpret_cast<const bf16x8_t*>(
          Vb + base + (size_t)(nt * 16 + l15) * 64 + kt * 32 + quad * 8);
#pragma unroll
      for (int j = 0; j < 8; ++j)
        vo.u[j] = f2bfbits(bfbits2f(vr.u[j]) * ksv[kt][j]);
      vs[nt][kt] = vo.v;
    }

  // Q fragments + qn partials
  bf16x8_t qf[4][2];
  float qn[4] = {0.f, 0.f, 0.f, 0.f};
#pragma unroll
  for (int mt = 0; mt < 4; ++mt)
#pragma unroll
    for (int kt = 0; kt < 2; ++kt) {
      VU qr;
      qr.v = *reinterpret_cast<const bf16x8_t*>(
          Qb + base + (size_t)(mt * 16 + l15) * 64 + kt * 32 + quad * 8);
      qf[mt][kt] = qr.v;
#pragma unroll
      for (int j = 0; j < 8; ++j)
        qn[mt] += bfbits2f(qr.u[j]) * ksv[kt][j];
    }
#pragma unroll
  for (int mt = 0; mt < 4; ++mt) {
    qn[mt] += __shfl_xor(qn[mt], 16, 64);
    qn[mt] += __shfl_xor(qn[mt], 32, 64);  // now qn for row mt*16+l15 on all lanes
  }

  f32x4_t acc[4][4];
#pragma unroll
  for (int mt = 0; mt < 4; ++mt)
#pragma unroll
    for (int nt = 0; nt < 4; ++nt) acc[mt][nt] = (f32x4_t){0.f, 0.f, 0.f, 0.f};

#pragma unroll
  for (int mt = 0; mt < 4; ++mt)
#pragma unroll
    for (int nt = 0; nt < 4; ++nt) {
      acc[mt][nt] = __builtin_amdgcn_mfma_f32_16x16x32_bf16(
          qf[mt][0], vs[nt][0], acc[mt][nt], 0, 0, 0);
      acc[mt][nt] = __builtin_amdgcn_mfma_f32_16x16x32_bf16(
          qf[mt][1], vs[nt][1], acc[mt][nt], 0, 0, 0);
    }

  // epilogue: row = mt*16 + quad*4 + i (qn lives on lane l15' = quad*4+i)
#pragma unroll
  for (int mt = 0; mt < 4; ++mt)
#pragma unroll
    for (int i = 0; i < 4; ++i) {
      const float inv = 1.f / (__shfl(qn[mt], quad * 4 + i, 64) + EPS);
      const size_t roff = base + (size_t)(mt * 16 + quad * 4 + i) * 64;
#pragma unroll
      for (int nt = 0; nt < 4; ++nt)
        Ab[roff + nt * 16 + l15] = f2bfbits(acc[mt][nt][i] * inv);
    }
}

// ---------------------------------------------------------------------------
// Buffers:
//  ws   @0      : Q (bf16 8192x4096, 64MB) -> A (attn writes in place)
//  ws   @64MB   : K -> V (bf16, 64MB); first 8MB reused for Wo^T after attn
//  ws   @128MB  : ksum (fp32 8192x64, 2MB)          (total ws = 130MB)
//  d_out@0      : Xb (bf16 8192x1024, 16MB)  — dead before gemm_out writes
//  d_out@16MB   : Wt (bf16 4096x1024, 8MB) for Wk/Wv/Wq — dead before gemm_out
// ---------------------------------------------------------------------------
extern "C" void kernel_launch(void* const* d_in, const int* in_sizes, int n_in,
                              void* d_out, int out_size, void* d_ws, size_t ws_size,
                              hipStream_t stream)
{
  const float* x  = (const float*)d_in[0];
  const float* Wq = (const float*)d_in[1];
  const float* Wk = (const float*)d_in[2];
  const float* Wv = (const float*)d_in[3];
  const float* Wo = (const float*)d_in[4];
  const float* bo = (const float*)d_in[5];
  float* out = (float*)d_out;

  uint8_t* ws = (uint8_t*)d_ws;
  const size_t QK_BYTES = (size_t)M_TOK * INNER * sizeof(bf16);  // 64 MB
  unsigned short* Qb  = (unsigned short*)ws;                      // Q then A
  unsigned short* KVb = (unsigned short*)(ws + QK_BYTES);         // K then V; then Wo^T
  float* ks           = (float*)(ws + 2 * QK_BYTES);

  unsigned short* Xb = (unsigned short*)d_out;                          // 16 MB
  unsigned short* Wt = (unsigned short*)((uint8_t*)d_out + (16u << 20)); // 8 MB
  unsigned short* Wot = KVb;  // Wo^T over dead V (after attn)

  const dim3 blk(256);
  const dim3 gproj(INNER / 128, M_TOK / 128);  // 32 x 64
  const dim3 gout(DIM / 64, M_TOK / 128);      // 16 x 64
  const dim3 gtc(INNER / 32, DIM / 32);        // W [1024][4096] -> [4096][1024]
  const dim3 gtco(DIM / 32, INNER / 32);       // Wo [4096][1024] -> [1024][4096]

  castx_kernel<<<dim3((M_TOK * DIM / 4 + 255) / 256), blk, 0, stream>>>(
      x, Xb, M_TOK * DIM / 4);

  tcast_kernel<<<gtc, blk, 0, stream>>>(Wk, Wt, DIM, INNER);
  gemm_bf16<1><<<gproj, blk, 0, stream>>>(Xb, Wt, KVb, M_TOK, INNER, DIM);  // K
  ksum_kernel<<<dim3(M_TOK / 4), blk, 0, stream>>>(KVb, ks);

  tcast_kernel<<<gtc, blk, 0, stream>>>(Wv, Wt, DIM, INNER);
  gemm_bf16<0><<<gproj, blk, 0, stream>>>(Xb, Wt, KVb, M_TOK, INNER, DIM);  // V

  tcast_kernel<<<gtc, blk, 0, stream>>>(Wq, Wt, DIM, INNER);
  gemm_bf16<2><<<gproj, blk, 0, stream>>>(Xb, Wt, Qb, M_TOK, INNER, DIM);   // Q

  attn_mfma<<<dim3(M_TOK / 4), blk, 0, stream>>>(Qb, KVb, ks, Qb);  // A aliases Q

  tcast_kernel<<<gtco, blk, 0, stream>>>(Wo, Wot, INNER, DIM);
  gemm_out_bf16<<<gout, blk, 0, stream>>>(Qb, Wot, bo, out, M_TOK, DIM, INNER);
}

// Round 4
// 543.582 us; speedup vs baseline: 6.3334x; 1.0360x over previous
//
#include <hip/hip_runtime.h>
#include <hip/hip_bf16.h>
#include <cstdint>

// Problem constants (b=2, s=4096, dim=1024, heads=64, dim_head=64)
#define M_TOK 8192
#define DIM   1024
#define INNER 4096
#define HEADS 64
#define DH    64
#define QSCALE 0.125f      // 64^-0.5
#define EPS    1e-6f

typedef __hip_bfloat16 bf16;
typedef __bf16 bf16x8_t __attribute__((ext_vector_type(8)));
typedef float f32x4_t __attribute__((ext_vector_type(4)));

__device__ __forceinline__ float bfbits2f(unsigned short u) {
  return __uint_as_float(((unsigned)u) << 16);
}
__device__ __forceinline__ unsigned short f2bfbits(float f) {
  __hip_bfloat16 h = __float2bfloat16(f);
  unsigned short u;
  __builtin_memcpy(&u, &h, 2);
  return u;
}

// async global->LDS, 16B per lane. LDS dst must be wave-uniform base + lane*16.
__device__ __forceinline__ void load_lds16(const void* g, void* l) {
  __builtin_amdgcn_global_load_lds(
      (__attribute__((address_space(1))) void*)g,
      (__attribute__((address_space(3))) void*)l, 16, 0, 0);
}

// XCD-aware block swizzle: XCD x owns M-tiles [x*gy/8, (x+1)*gy/8), N-major
// within the XCD so consecutive same-XCD blocks share A-tiles in its L2.
// (R3: cut gemm_out FETCH_SIZE 270->66 MB.)
__device__ __forceinline__ void swizzle_xy(int& bx, int& by) {
  const int gx = gridDim.x, gy = gridDim.y;
  const int id  = blockIdx.x + gx * blockIdx.y;
  const int per = gy >> 3;          // M-tiles per XCD (gy % 8 == 0)
  const int xcd = id & 7;
  const int s   = id >> 3;
  by = xcd * per + (s % per);
  bx = s / per;
}

// ---------------------------------------------------------------------------
// cast x (fp32) -> bf16, same layout. One float4 per thread.
// ---------------------------------------------------------------------------
__global__ __launch_bounds__(256) void castx_kernel(
    const float* __restrict__ x, unsigned short* __restrict__ xb, int n4)
{
  const int i = blockIdx.x * 256 + threadIdx.x;
  if (i < n4) {
    const float4 v = reinterpret_cast<const float4*>(x)[i];
    ushort4 o;
    o.x = f2bfbits(v.x); o.y = f2bfbits(v.y);
    o.z = f2bfbits(v.z); o.w = f2bfbits(v.w);
    reinterpret_cast<ushort4*>(xb)[i] = o;
  }
}

// ---------------------------------------------------------------------------
// transpose-cast: W [R][C] fp32 -> Wt [C][R] bf16.  32x32 LDS tiles.
// ---------------------------------------------------------------------------
__global__ __launch_bounds__(256) void tcast_kernel(
    const float* __restrict__ W, unsigned short* __restrict__ Wt, int R, int C)
{
  __shared__ float tile[32][33];
  const int bx = blockIdx.x * 32;   // C offset
  const int by = blockIdx.y * 32;   // R offset
  const int tx = threadIdx.x & 31;
  const int ty = threadIdx.x >> 5;  // 0..7
#pragma unroll
  for (int k = 0; k < 4; ++k)
    tile[ty + k * 8][tx] = W[(size_t)(by + ty + k * 8) * C + bx + tx];
  __syncthreads();
#pragma unroll
  for (int k = 0; k < 4; ++k)
    Wt[(size_t)(bx + ty + k * 8) * R + by + tx] = f2bfbits(tile[tx][ty + k * 8]);
}

// Dual version: z=0 -> W0 into Wt[0:C*R), z=1 -> W1 into Wt[C*R:2*C*R).
__global__ __launch_bounds__(256) void tcast_dual_kernel(
    const float* __restrict__ W0, const float* __restrict__ W1,
    unsigned short* __restrict__ Wt, int R, int C)
{
  __shared__ float tile[32][33];
  const float* W = blockIdx.z ? W1 : W0;
  unsigned short* dst = Wt + (size_t)blockIdx.z * R * C;
  const int bx = blockIdx.x * 32;
  const int by = blockIdx.y * 32;
  const int tx = threadIdx.x & 31;
  const int ty = threadIdx.x >> 5;
#pragma unroll
  for (int k = 0; k < 4; ++k)
    tile[ty + k * 8][tx] = W[(size_t)(by + ty + k * 8) * C + bx + tx];
  __syncthreads();
#pragma unroll
  for (int k = 0; k < 4; ++k)
    dst[(size_t)(bx + ty + k * 8) * R + by + tx] = f2bfbits(tile[tx][ty + k * 8]);
}

// ---------------------------------------------------------------------------
// MFMA GEMM: C[M,N] = act(A[M,K] @ Bt[N,K]^T), all bf16, fp32 accumulate.
// 128x128 tile, BK=32, 256 threads (4 waves, 2x2), 4x4 16x16x32 MFMAs/wave.
// MODE: 2 = relu*QSCALE (Q projection)
// ---------------------------------------------------------------------------
template <int MODE>
__global__ __launch_bounds__(256) void gemm_bf16(
    const unsigned short* __restrict__ A,   // [M][K] bf16
    const unsigned short* __restrict__ Bt,  // [N][K] bf16 (B transposed)
    unsigned short* __restrict__ C,         // [M][N] bf16
    int M, int N, int K)
{
  __shared__ __align__(16) unsigned short As[128 * 32];
  __shared__ __align__(16) unsigned short Bs[128 * 32];

  int bxi, byi;
  swizzle_xy(bxi, byi);
  const int tid  = threadIdx.x;
  const int bm   = byi * 128;
  const int bn   = bxi * 128;
  const int lane = tid & 63;
  const int w    = tid >> 6;
  const int wm   = (w & 1) * 64;
  const int wn   = (w >> 1) * 64;
  const int quad = lane >> 4;
  const int l15  = lane & 15;

  f32x4_t acc[4][4];
#pragma unroll
  for (int mt = 0; mt < 4; ++mt)
#pragma unroll
    for (int nt = 0; nt < 4; ++nt) acc[mt][nt] = (f32x4_t){0.f, 0.f, 0.f, 0.f};

  const int q0 = tid, q1 = tid + 256;
  const int row0 = q0 >> 2, row1 = q1 >> 2;
  const int c0 = (q0 & 3) ^ ((q0 >> 3) & 3);
  const int c1 = (q1 & 3) ^ ((q1 >> 3) & 3);

  for (int k0 = 0; k0 < K; k0 += 32) {
    __syncthreads();
    load_lds16(&A [(size_t)(bm + row0) * K + k0 + c0 * 8], &As[q0 * 8]);
    load_lds16(&Bt[(size_t)(bn + row0) * K + k0 + c0 * 8], &Bs[q0 * 8]);
    load_lds16(&A [(size_t)(bm + row1) * K + k0 + c1 * 8], &As[q1 * 8]);
    load_lds16(&Bt[(size_t)(bn + row1) * K + k0 + c1 * 8], &Bs[q1 * 8]);
    __syncthreads();

    bf16x8_t af[4], bfr[4];
#pragma unroll
    for (int mt = 0; mt < 4; ++mt) {
      const int r  = wm + mt * 16 + l15;
      const int cp = quad ^ ((r >> 1) & 3);
      af[mt] = *reinterpret_cast<const bf16x8_t*>(&As[r * 32 + cp * 8]);
    }
#pragma unroll
    for (int nt = 0; nt < 4; ++nt) {
      const int r  = wn + nt * 16 + l15;
      const int cp = quad ^ ((r >> 1) & 3);
      bfr[nt] = *reinterpret_cast<const bf16x8_t*>(&Bs[r * 32 + cp * 8]);
    }
#pragma unroll
    for (int mt = 0; mt < 4; ++mt)
#pragma unroll
      for (int nt = 0; nt < 4; ++nt)
        acc[mt][nt] = __builtin_amdgcn_mfma_f32_16x16x32_bf16(
            af[mt], bfr[nt], acc[mt][nt], 0, 0, 0);
  }

#pragma unroll
  for (int mt = 0; mt < 4; ++mt)
#pragma unroll
    for (int i = 0; i < 4; ++i) {
      const size_t rowg = (size_t)(bm + wm + mt * 16 + quad * 4 + i);
#pragma unroll
      for (int nt = 0; nt < 4; ++nt) {
        float v = acc[mt][nt][i];
        if (MODE >= 1) v = fmaxf(v, 0.f);
        if (MODE == 2) v *= QSCALE;
        C[rowg * N + bn + wn + nt * 16 + l15] = f2bfbits(v);
      }
    }
}

// ---------------------------------------------------------------------------
// Fused K+V projection: Bt = [Wk^T ; Wv^T] as [8192][1024].
// Tiles with bn<4096 -> relu -> Kb; bn>=4096 -> identity -> Vb.
// (128-col tiles never straddle the 4096 boundary.)
// ---------------------------------------------------------------------------
__global__ __launch_bounds__(256) void gemm_kv(
    const unsigned short* __restrict__ A,    // Xb [8192][1024]
    const unsigned short* __restrict__ Bt,   // [8192][1024]
    unsigned short* __restrict__ Kb,         // [8192][4096]
    unsigned short* __restrict__ Vb,         // [8192][4096]
    int K)
{
  __shared__ __align__(16) unsigned short As[128 * 32];
  __shared__ __align__(16) unsigned short Bs[128 * 32];

  int bxi, byi;
  swizzle_xy(bxi, byi);
  const int tid  = threadIdx.x;
  const int bm   = byi * 128;
  const int bn   = bxi * 128;
  const bool isK = (bn < 4096);
  unsigned short* __restrict__ C = isK ? Kb : Vb;
  const int bnc  = bn & 4095;
  const int lane = tid & 63;
  const int w    = tid >> 6;
  const int wm   = (w & 1) * 64;
  const int wn   = (w >> 1) * 64;
  const int quad = lane >> 4;
  const int l15  = lane & 15;

  f32x4_t acc[4][4];
#pragma unroll
  for (int mt = 0; mt < 4; ++mt)
#pragma unroll
    for (int nt = 0; nt < 4; ++nt) acc[mt][nt] = (f32x4_t){0.f, 0.f, 0.f, 0.f};

  const int q0 = tid, q1 = tid + 256;
  const int row0 = q0 >> 2, row1 = q1 >> 2;
  const int c0 = (q0 & 3) ^ ((q0 >> 3) & 3);
  const int c1 = (q1 & 3) ^ ((q1 >> 3) & 3);

  for (int k0 = 0; k0 < K; k0 += 32) {
    __syncthreads();
    load_lds16(&A [(size_t)(bm + row0) * K + k0 + c0 * 8], &As[q0 * 8]);
    load_lds16(&Bt[(size_t)(bn + row0) * K + k0 + c0 * 8], &Bs[q0 * 8]);
    load_lds16(&A [(size_t)(bm + row1) * K + k0 + c1 * 8], &As[q1 * 8]);
    load_lds16(&Bt[(size_t)(bn + row1) * K + k0 + c1 * 8], &Bs[q1 * 8]);
    __syncthreads();

    bf16x8_t af[4], bfr[4];
#pragma unroll
    for (int mt = 0; mt < 4; ++mt) {
      const int r  = wm + mt * 16 + l15;
      const int cp = quad ^ ((r >> 1) & 3);
      af[mt] = *reinterpret_cast<const bf16x8_t*>(&As[r * 32 + cp * 8]);
    }
#pragma unroll
    for (int nt = 0; nt < 4; ++nt) {
      const int r  = wn + nt * 16 + l15;
      const int cp = quad ^ ((r >> 1) & 3);
      bfr[nt] = *reinterpret_cast<const bf16x8_t*>(&Bs[r * 32 + cp * 8]);
    }
#pragma unroll
    for (int mt = 0; mt < 4; ++mt)
#pragma unroll
      for (int nt = 0; nt < 4; ++nt)
        acc[mt][nt] = __builtin_amdgcn_mfma_f32_16x16x32_bf16(
            af[mt], bfr[nt], acc[mt][nt], 0, 0, 0);
  }

#pragma unroll
  for (int mt = 0; mt < 4; ++mt)
#pragma unroll
    for (int i = 0; i < 4; ++i) {
      const size_t rowg = (size_t)(bm + wm + mt * 16 + quad * 4 + i);
#pragma unroll
      for (int nt = 0; nt < 4; ++nt) {
        float v = acc[mt][nt][i];
        if (isK) v = fmaxf(v, 0.f);
        C[rowg * 4096 + bnc + wn + nt * 16 + l15] = f2bfbits(v);
      }
    }
}

// ---------------------------------------------------------------------------
// Output MFMA GEMM: out[M,N] = A[M,K] @ Bt[N,K]^T + bias[N], fp32 out.
// 128(M) x 64(N) tile, BK=64 (halved barrier count vs R3; 16 MFMA/wave/iter).
// LDS rows are 8 x 16B chunks, xor swizzle slot = chunk ^ (row&7):
// staging stays lane-contiguous, fragment ds_read_b128 2-way banked (free).
// ---------------------------------------------------------------------------
__global__ __launch_bounds__(256) void gemm_out_bf16(
    const unsigned short* __restrict__ A,   // [M][K] bf16
    const unsigned short* __restrict__ Bt,  // [N][K] bf16
    const float* __restrict__ bias,
    float* __restrict__ out, int M, int N, int K)
{
  __shared__ __align__(16) unsigned short As[128 * 64];  // 16 KB
  __shared__ __align__(16) unsigned short Bs[64 * 64];   //  8 KB

  int bxi, byi;
  swizzle_xy(bxi, byi);
  const int tid  = threadIdx.x;
  const int bm   = byi * 128;
  const int bn   = bxi * 64;
  const int lane = tid & 63;
  const int w    = tid >> 6;
  const int wm   = (w & 1) * 64;
  const int wn   = (w >> 1) * 32;
  const int quad = lane >> 4;
  const int l15  = lane & 15;

  f32x4_t acc[4][2];
#pragma unroll
  for (int mt = 0; mt < 4; ++mt)
#pragma unroll
    for (int nt = 0; nt < 2; ++nt) acc[mt][nt] = (f32x4_t){0.f, 0.f, 0.f, 0.f};

  // A: 1024 chunks (4/thread); B: 512 chunks (2/thread). row = q>>3,
  // stored slot = q&7, global chunk c = slot ^ (row&7).
  int qa[4], ra[4], ca[4];
#pragma unroll
  for (int j = 0; j < 4; ++j) {
    qa[j] = tid + 256 * j;
    ra[j] = qa[j] >> 3;
    ca[j] = (qa[j] & 7) ^ (ra[j] & 7);
  }
  int qb[2], rb[2], cb[2];
#pragma unroll
  for (int j = 0; j < 2; ++j) {
    qb[j] = tid + 256 * j;
    rb[j] = qb[j] >> 3;
    cb[j] = (qb[j] & 7) ^ (rb[j] & 7);
  }

  for (int k0 = 0; k0 < K; k0 += 64) {
    __syncthreads();
#pragma unroll
    for (int j = 0; j < 4; ++j)
      load_lds16(&A[(size_t)(bm + ra[j]) * K + k0 + ca[j] * 8], &As[qa[j] * 8]);
#pragma unroll
    for (int j = 0; j < 2; ++j)
      load_lds16(&Bt[(size_t)(bn + rb[j]) * K + k0 + cb[j] * 8], &Bs[qb[j] * 8]);
    __syncthreads();

    bf16x8_t af[4][2], bfr[2][2];
#pragma unroll
    for (int mt = 0; mt < 4; ++mt) {
      const int r = wm + mt * 16 + l15;
#pragma unroll
      for (int kt = 0; kt < 2; ++kt) {
        const int slot = (kt * 4 + quad) ^ (r & 7);
        af[mt][kt] = *reinterpret_cast<const bf16x8_t*>(&As[r * 64 + slot * 8]);
      }
    }
#pragma unroll
    for (int nt = 0; nt < 2; ++nt) {
      const int r = wn + nt * 16 + l15;
#pragma unroll
      for (int kt = 0; kt < 2; ++kt) {
        const int slot = (kt * 4 + quad) ^ (r & 7);
        bfr[nt][kt] = *reinterpret_cast<const bf16x8_t*>(&Bs[r * 64 + slot * 8]);
      }
    }
#pragma unroll
    for (int mt = 0; mt < 4; ++mt)
#pragma unroll
      for (int nt = 0; nt < 2; ++nt) {
        acc[mt][nt] = __builtin_amdgcn_mfma_f32_16x16x32_bf16(
            af[mt][0], bfr[nt][0], acc[mt][nt], 0, 0, 0);
        acc[mt][nt] = __builtin_amdgcn_mfma_f32_16x16x32_bf16(
            af[mt][1], bfr[nt][1], acc[mt][nt], 0, 0, 0);
      }
  }

#pragma unroll
  for (int mt = 0; mt < 4; ++mt)
#pragma unroll
    for (int i = 0; i < 4; ++i) {
      const size_t rowg = (size_t)(bm + wm + mt * 16 + quad * 4 + i);
#pragma unroll
      for (int nt = 0; nt < 2; ++nt) {
        const int colg = bn + wn + nt * 16 + l15;
        out[rowg * N + colg] = acc[mt][nt][i] + bias[colg];
      }
    }
}

// ---------------------------------------------------------------------------
// ksum[t][d] = sum_i K[t][i*64+d].  One wave per token, 4 tokens/block.
// ---------------------------------------------------------------------------
__global__ __launch_bounds__(256) void ksum_kernel(
    const unsigned short* __restrict__ Kb, float* __restrict__ ks)
{
  const int t = blockIdx.x * 4 + (threadIdx.x >> 6);
  const int j = threadIdx.x & 63;
  const uint4* row = reinterpret_cast<const uint4*>(Kb + (size_t)t * INNER);
  float s[8] = {0.f, 0.f, 0.f, 0.f, 0.f, 0.f, 0.f, 0.f};
#pragma unroll
  for (int m = 0; m < 8; ++m) {
    const uint4 u = row[j + 64 * m];
    s[0] += __uint_as_float((u.x & 0xFFFFu) << 16);
    s[1] += __uint_as_float(u.x & 0xFFFF0000u);
    s[2] += __uint_as_float((u.y & 0xFFFFu) << 16);
    s[3] += __uint_as_float(u.y & 0xFFFF0000u);
    s[4] += __uint_as_float((u.z & 0xFFFFu) << 16);
    s[5] += __uint_as_float(u.z & 0xFFFF0000u);
    s[6] += __uint_as_float((u.w & 0xFFFFu) << 16);
    s[7] += __uint_as_float(u.w & 0xFFFF0000u);
  }
#pragma unroll
  for (int off = 8; off < 64; off <<= 1)
#pragma unroll
    for (int e = 0; e < 8; ++e) s[e] += __shfl_xor(s[e], off, 64);
  if (j < 8) {
    float4* dst = reinterpret_cast<float4*>(ks + t * 64 + j * 8);
    float4 lo, hi;
    lo.x = s[0]; lo.y = s[1]; lo.z = s[2]; lo.w = s[3];
    hi.x = s[4]; hi.y = s[5]; hi.z = s[6]; hi.w = s[7];
    dst[0] = lo; dst[1] = hi;
  }
}

// ---------------------------------------------------------------------------
// MFMA attention: one wave per token, 4 tokens/block, zero LDS (R3-verified).
// ---------------------------------------------------------------------------
__global__ __launch_bounds__(256) void attn_mfma(
    const unsigned short* __restrict__ Qb, const unsigned short* __restrict__ Vb,
    const float* __restrict__ ksum, unsigned short* __restrict__ Ab)
{
  const int t    = blockIdx.x * 4 + (threadIdx.x >> 6);
  const int lane = threadIdx.x & 63;
  const int l15  = lane & 15;
  const int quad = lane >> 4;
  const size_t base = (size_t)t * INNER;

  union VU { bf16x8_t v; unsigned short u[8]; };

  float ksv[2][8];
#pragma unroll
  for (int kt = 0; kt < 2; ++kt) {
    const float4* p = reinterpret_cast<const float4*>(ksum + t * 64 + kt * 32 + quad * 8);
    const float4 a = p[0], b = p[1];
    ksv[kt][0] = a.x; ksv[kt][1] = a.y; ksv[kt][2] = a.z; ksv[kt][3] = a.w;
    ksv[kt][4] = b.x; ksv[kt][5] = b.y; ksv[kt][6] = b.z; ksv[kt][7] = b.w;
  }

  bf16x8_t vs[4][2];
#pragma unroll
  for (int nt = 0; nt < 4; ++nt)
#pragma unroll
    for (int kt = 0; kt < 2; ++kt) {
      VU vr, vo;
      vr.v = *reinterpret_cast<const bf16x8_t*>(
          Vb + base + (size_t)(nt * 16 + l15) * 64 + kt * 32 + quad * 8);
#pragma unroll
      for (int j = 0; j < 8; ++j)
        vo.u[j] = f2bfbits(bfbits2f(vr.u[j]) * ksv[kt][j]);
      vs[nt][kt] = vo.v;
    }

  bf16x8_t qf[4][2];
  float qn[4] = {0.f, 0.f, 0.f, 0.f};
#pragma unroll
  for (int mt = 0; mt < 4; ++mt)
#pragma unroll
    for (int kt = 0; kt < 2; ++kt) {
      VU qr;
      qr.v = *reinterpret_cast<const bf16x8_t*>(
          Qb + base + (size_t)(mt * 16 + l15) * 64 + kt * 32 + quad * 8);
      qf[mt][kt] = qr.v;
#pragma unroll
      for (int j = 0; j < 8; ++j)
        qn[mt] += bfbits2f(qr.u[j]) * ksv[kt][j];
    }
#pragma unroll
  for (int mt = 0; mt < 4; ++mt) {
    qn[mt] += __shfl_xor(qn[mt], 16, 64);
    qn[mt] += __shfl_xor(qn[mt], 32, 64);
  }

  f32x4_t acc[4][4];
#pragma unroll
  for (int mt = 0; mt < 4; ++mt)
#pragma unroll
    for (int nt = 0; nt < 4; ++nt) acc[mt][nt] = (f32x4_t){0.f, 0.f, 0.f, 0.f};

#pragma unroll
  for (int mt = 0; mt < 4; ++mt)
#pragma unroll
    for (int nt = 0; nt < 4; ++nt) {
      acc[mt][nt] = __builtin_amdgcn_mfma_f32_16x16x32_bf16(
          qf[mt][0], vs[nt][0], acc[mt][nt], 0, 0, 0);
      acc[mt][nt] = __builtin_amdgcn_mfma_f32_16x16x32_bf16(
          qf[mt][1], vs[nt][1], acc[mt][nt], 0, 0, 0);
    }

#pragma unroll
  for (int mt = 0; mt < 4; ++mt)
#pragma unroll
    for (int i = 0; i < 4; ++i) {
      const float inv = 1.f / (__shfl(qn[mt], quad * 4 + i, 64) + EPS);
      const size_t roff = base + (size_t)(mt * 16 + quad * 4 + i) * 64;
#pragma unroll
      for (int nt = 0; nt < 4; ++nt)
        Ab[roff + nt * 16 + l15] = f2bfbits(acc[mt][nt][i] * inv);
    }
}

// ---------------------------------------------------------------------------
// Buffers (ws = 130 MB as before):
//  ws   @0      : K (transient) -> Q -> A (in place)
//  ws   @64MB   : V ; first 8MB reused for Wo^T after attn
//  ws   @128MB  : ksum (fp32 8192x64, 2MB)
//  d_out@0      : Xb (bf16 8192x1024, 16MB)       — dead before gemm_out writes
//  d_out@16MB   : WtKV (bf16 8192x1024, 16MB)     — then WqT (8MB)
// Order: castx, tcast(Wk,Wv), gemmKV(K->ws0,V->ws64), ksum(ws0),
//        tcast(Wq), gemmQ(->ws0), attn(ws0,ws64 -> ws0), tcast(Wo->ws64),
//        gemm_out(ws0 x ws64 -> d_out).
// ---------------------------------------------------------------------------
extern "C" void kernel_launch(void* const* d_in, const int* in_sizes, int n_in,
                              void* d_out, int out_size, void* d_ws, size_t ws_size,
                              hipStream_t stream)
{
  const float* x  = (const float*)d_in[0];
  const float* Wq = (const float*)d_in[1];
  const float* Wk = (const float*)d_in[2];
  const float* Wv = (const float*)d_in[3];
  const float* Wo = (const float*)d_in[4];
  const float* bo = (const float*)d_in[5];
  float* out = (float*)d_out;

  uint8_t* ws = (uint8_t*)d_ws;
  const size_t HALF = (size_t)M_TOK * INNER * sizeof(bf16);  // 64 MB
  unsigned short* KQA = (unsigned short*)ws;            // K -> Q -> A
  unsigned short* Vb  = (unsigned short*)(ws + HALF);   // V ; then Wo^T
  float* ks           = (float*)(ws + 2 * HALF);

  unsigned short* Xb   = (unsigned short*)d_out;                           // 16 MB
  unsigned short* WtKV = (unsigned short*)((uint8_t*)d_out + (16u << 20)); // 16 MB
  unsigned short* WqT  = WtKV;   // reused after gemm_kv
  unsigned short* Wot  = Vb;     // Wo^T over dead V (after attn)

  const dim3 blk(256);

  castx_kernel<<<dim3(M_TOK * DIM / 4 / 256), blk, 0, stream>>>(
      x, Xb, M_TOK * DIM / 4);

  // Wk^T and Wv^T stacked -> WtKV [8192][1024]
  tcast_dual_kernel<<<dim3(INNER / 32, DIM / 32, 2), blk, 0, stream>>>(
      Wk, Wv, WtKV, DIM, INNER);

  gemm_kv<<<dim3(2 * INNER / 128, M_TOK / 128), blk, 0, stream>>>(
      Xb, WtKV, KQA, Vb, DIM);

  ksum_kernel<<<dim3(M_TOK / 4), blk, 0, stream>>>(KQA, ks);

  tcast_kernel<<<dim3(INNER / 32, DIM / 32), blk, 0, stream>>>(
      Wq, WqT, DIM, INNER);

  gemm_bf16<2><<<dim3(INNER / 128, M_TOK / 128), blk, 0, stream>>>(
      Xb, WqT, KQA, M_TOK, INNER, DIM);  // Q overwrites dead K

  attn_mfma<<<dim3(M_TOK / 4), blk, 0, stream>>>(KQA, Vb, ks, KQA);  // A in place

  tcast_kernel<<<dim3(DIM / 32, INNER / 32), blk, 0, stream>>>(
      Wo, Wot, INNER, DIM);  // over dead V

  gemm_out_bf16<<<dim3(DIM / 64, M_TOK / 128), blk, 0, stream>>>(
      KQA, Wot, bo, out, M_TOK, DIM, INNER);
}

// Round 5
// 500.730 us; speedup vs baseline: 6.8754x; 1.0856x over previous
//
#include <hip/hip_runtime.h>
#include <hip/hip_bf16.h>
#include <cstdint>

// Problem constants (b=2, s=4096, dim=1024, heads=64, dim_head=64)
#define M_TOK 8192
#define DIM   1024
#define INNER 4096
#define HEADS 64
#define DH    64
#define QSCALE 0.125f      // 64^-0.5
#define EPS    1e-6f

typedef __hip_bfloat16 bf16;
typedef __bf16 bf16x8_t __attribute__((ext_vector_type(8)));
typedef float f32x4_t __attribute__((ext_vector_type(4)));

__device__ __forceinline__ float bfbits2f(unsigned short u) {
  return __uint_as_float(((unsigned)u) << 16);
}
__device__ __forceinline__ unsigned short f2bfbits(float f) {
  __hip_bfloat16 h = __float2bfloat16(f);
  unsigned short u;
  __builtin_memcpy(&u, &h, 2);
  return u;
}

// async global->LDS, 16B per lane. LDS dst must be wave-uniform base + lane*16.
__device__ __forceinline__ void load_lds16(const void* g, void* l) {
  __builtin_amdgcn_global_load_lds(
      (__attribute__((address_space(1))) void*)g,
      (__attribute__((address_space(3))) void*)l, 16, 0, 0);
}

// XCD-aware block swizzle: XCD x owns M-tiles [x*gy/8, (x+1)*gy/8), N-major
// within the XCD. (R3: cut gemm_out FETCH_SIZE 270->66 MB.)
__device__ __forceinline__ void swizzle_xy(int& bx, int& by) {
  const int gx = gridDim.x, gy = gridDim.y;
  const int id  = blockIdx.x + gx * blockIdx.y;
  const int per = gy >> 3;          // M-tiles per XCD (gy % 8 == 0)
  const int xcd = id & 7;
  const int s   = id >> 3;
  by = xcd * per + (s % per);
  bx = s / per;
}

// ---------------------------------------------------------------------------
// cast x (fp32) -> bf16, same layout. One float4 per thread.
// ---------------------------------------------------------------------------
__global__ __launch_bounds__(256) void castx_kernel(
    const float* __restrict__ x, unsigned short* __restrict__ xb, int n4)
{
  const int i = blockIdx.x * 256 + threadIdx.x;
  if (i < n4) {
    const float4 v = reinterpret_cast<const float4*>(x)[i];
    ushort4 o;
    o.x = f2bfbits(v.x); o.y = f2bfbits(v.y);
    o.z = f2bfbits(v.z); o.w = f2bfbits(v.w);
    reinterpret_cast<ushort4*>(xb)[i] = o;
  }
}

// ---------------------------------------------------------------------------
// transpose-cast: W [R][C] fp32 -> Wt [C][R] bf16.  32x32 LDS tiles.
// ---------------------------------------------------------------------------
__global__ __launch_bounds__(256) void tcast_kernel(
    const float* __restrict__ W, unsigned short* __restrict__ Wt, int R, int C)
{
  __shared__ float tile[32][33];
  const int bx = blockIdx.x * 32;   // C offset
  const int by = blockIdx.y * 32;   // R offset
  const int tx = threadIdx.x & 31;
  const int ty = threadIdx.x >> 5;  // 0..7
#pragma unroll
  for (int k = 0; k < 4; ++k)
    tile[ty + k * 8][tx] = W[(size_t)(by + ty + k * 8) * C + bx + tx];
  __syncthreads();
#pragma unroll
  for (int k = 0; k < 4; ++k)
    Wt[(size_t)(bx + ty + k * 8) * R + by + tx] = f2bfbits(tile[tx][ty + k * 8]);
}

// Dual version: z=0 -> W0 into Wt[0:C*R), z=1 -> W1 into Wt[C*R:2*C*R).
__global__ __launch_bounds__(256) void tcast_dual_kernel(
    const float* __restrict__ W0, const float* __restrict__ W1,
    unsigned short* __restrict__ Wt, int R, int C)
{
  __shared__ float tile[32][33];
  const float* W = blockIdx.z ? W1 : W0;
  unsigned short* dst = Wt + (size_t)blockIdx.z * R * C;
  const int bx = blockIdx.x * 32;
  const int by = blockIdx.y * 32;
  const int tx = threadIdx.x & 31;
  const int ty = threadIdx.x >> 5;
#pragma unroll
  for (int k = 0; k < 4; ++k)
    tile[ty + k * 8][tx] = W[(size_t)(by + ty + k * 8) * C + bx + tx];
  __syncthreads();
#pragma unroll
  for (int k = 0; k < 4; ++k)
    dst[(size_t)(bx + ty + k * 8) * R + by + tx] = f2bfbits(tile[tx][ty + k * 8]);
}

// ---------------------------------------------------------------------------
// MFMA GEMM, 128x128 tile, BK=64: 32 MFMA/wave between barriers (vs 16 at
// BK=32), half the vmcnt(0) drains. LDS 2x16KB = 32KB -> still 3 blocks/CU
// (VGPR-capped), avoiding the BK=128 occupancy cliff.
// LDS rows = 8 x 16B chunks; stored slot = chunk ^ (row&7): staging stays
// lane-contiguous, fragment ds_read_b128 is 2-way banked (free).
// MODE: 0 = identity, 1 = relu, 2 = relu*QSCALE
// ---------------------------------------------------------------------------
template <int MODE>
__global__ __launch_bounds__(256) void gemm_bf16(
    const unsigned short* __restrict__ A,   // [M][K] bf16
    const unsigned short* __restrict__ Bt,  // [N][K] bf16 (B transposed)
    unsigned short* __restrict__ C,         // [M][N] bf16
    int M, int N, int K)
{
  __shared__ __align__(16) unsigned short As[128 * 64];  // 16 KB
  __shared__ __align__(16) unsigned short Bs[128 * 64];  // 16 KB

  int bxi, byi;
  swizzle_xy(bxi, byi);
  const int tid  = threadIdx.x;
  const int bm   = byi * 128;
  const int bn   = bxi * 128;
  const int lane = tid & 63;
  const int w    = tid >> 6;
  const int wm   = (w & 1) * 64;
  const int wn   = (w >> 1) * 64;
  const int quad = lane >> 4;
  const int l15  = lane & 15;

  f32x4_t acc[4][4];
#pragma unroll
  for (int mt = 0; mt < 4; ++mt)
#pragma unroll
    for (int nt = 0; nt < 4; ++nt) acc[mt][nt] = (f32x4_t){0.f, 0.f, 0.f, 0.f};

  // 1024 chunks per array, 4/thread. row = q>>3, slot = q&7, c = slot^(row&7)
  int qa[4], ra[4], ca[4];
#pragma unroll
  for (int j = 0; j < 4; ++j) {
    qa[j] = tid + 256 * j;
    ra[j] = qa[j] >> 3;
    ca[j] = (qa[j] & 7) ^ (ra[j] & 7);
  }

  for (int k0 = 0; k0 < K; k0 += 64) {
    __syncthreads();
#pragma unroll
    for (int j = 0; j < 4; ++j) {
      load_lds16(&A [(size_t)(bm + ra[j]) * K + k0 + ca[j] * 8], &As[qa[j] * 8]);
      load_lds16(&Bt[(size_t)(bn + ra[j]) * K + k0 + ca[j] * 8], &Bs[qa[j] * 8]);
    }
    __syncthreads();

    bf16x8_t af[4][2], bfr[4][2];
#pragma unroll
    for (int mt = 0; mt < 4; ++mt) {
      const int r = wm + mt * 16 + l15;
#pragma unroll
      for (int kt = 0; kt < 2; ++kt) {
        const int slot = (kt * 4 + quad) ^ (r & 7);
        af[mt][kt] = *reinterpret_cast<const bf16x8_t*>(&As[r * 64 + slot * 8]);
      }
    }
#pragma unroll
    for (int nt = 0; nt < 4; ++nt) {
      const int r = wn + nt * 16 + l15;
#pragma unroll
      for (int kt = 0; kt < 2; ++kt) {
        const int slot = (kt * 4 + quad) ^ (r & 7);
        bfr[nt][kt] = *reinterpret_cast<const bf16x8_t*>(&Bs[r * 64 + slot * 8]);
      }
    }
#pragma unroll
    for (int mt = 0; mt < 4; ++mt)
#pragma unroll
      for (int nt = 0; nt < 4; ++nt) {
        acc[mt][nt] = __builtin_amdgcn_mfma_f32_16x16x32_bf16(
            af[mt][0], bfr[nt][0], acc[mt][nt], 0, 0, 0);
        acc[mt][nt] = __builtin_amdgcn_mfma_f32_16x16x32_bf16(
            af[mt][1], bfr[nt][1], acc[mt][nt], 0, 0, 0);
      }
  }

#pragma unroll
  for (int mt = 0; mt < 4; ++mt)
#pragma unroll
    for (int i = 0; i < 4; ++i) {
      const size_t rowg = (size_t)(bm + wm + mt * 16 + quad * 4 + i);
#pragma unroll
      for (int nt = 0; nt < 4; ++nt) {
        float v = acc[mt][nt][i];
        if (MODE >= 1) v = fmaxf(v, 0.f);
        if (MODE == 2) v *= QSCALE;
        C[rowg * N + bn + wn + nt * 16 + l15] = f2bfbits(v);
      }
    }
}

// ---------------------------------------------------------------------------
// Fused K+V projection, BK=64, same structure. Bt = [Wk^T ; Wv^T] [8192][1024].
// Tiles with bn<4096 -> relu -> Kb; bn>=4096 -> identity -> Vb.
// ---------------------------------------------------------------------------
__global__ __launch_bounds__(256) void gemm_kv(
    const unsigned short* __restrict__ A,    // Xb [8192][1024]
    const unsigned short* __restrict__ Bt,   // [8192][1024]
    unsigned short* __restrict__ Kb,         // [8192][4096]
    unsigned short* __restrict__ Vb,         // [8192][4096]
    int K)
{
  __shared__ __align__(16) unsigned short As[128 * 64];
  __shared__ __align__(16) unsigned short Bs[128 * 64];

  int bxi, byi;
  swizzle_xy(bxi, byi);
  const int tid  = threadIdx.x;
  const int bm   = byi * 128;
  const int bn   = bxi * 128;
  const bool isK = (bn < 4096);
  unsigned short* __restrict__ C = isK ? Kb : Vb;
  const int bnc  = bn & 4095;
  const int lane = tid & 63;
  const int w    = tid >> 6;
  const int wm   = (w & 1) * 64;
  const int wn   = (w >> 1) * 64;
  const int quad = lane >> 4;
  const int l15  = lane & 15;

  f32x4_t acc[4][4];
#pragma unroll
  for (int mt = 0; mt < 4; ++mt)
#pragma unroll
    for (int nt = 0; nt < 4; ++nt) acc[mt][nt] = (f32x4_t){0.f, 0.f, 0.f, 0.f};

  int qa[4], ra[4], ca[4];
#pragma unroll
  for (int j = 0; j < 4; ++j) {
    qa[j] = tid + 256 * j;
    ra[j] = qa[j] >> 3;
    ca[j] = (qa[j] & 7) ^ (ra[j] & 7);
  }

  for (int k0 = 0; k0 < K; k0 += 64) {
    __syncthreads();
#pragma unroll
    for (int j = 0; j < 4; ++j) {
      load_lds16(&A [(size_t)(bm + ra[j]) * K + k0 + ca[j] * 8], &As[qa[j] * 8]);
      load_lds16(&Bt[(size_t)(bn + ra[j]) * K + k0 + ca[j] * 8], &Bs[qa[j] * 8]);
    }
    __syncthreads();

    bf16x8_t af[4][2], bfr[4][2];
#pragma unroll
    for (int mt = 0; mt < 4; ++mt) {
      const int r = wm + mt * 16 + l15;
#pragma unroll
      for (int kt = 0; kt < 2; ++kt) {
        const int slot = (kt * 4 + quad) ^ (r & 7);
        af[mt][kt] = *reinterpret_cast<const bf16x8_t*>(&As[r * 64 + slot * 8]);
      }
    }
#pragma unroll
    for (int nt = 0; nt < 4; ++nt) {
      const int r = wn + nt * 16 + l15;
#pragma unroll
      for (int kt = 0; kt < 2; ++kt) {
        const int slot = (kt * 4 + quad) ^ (r & 7);
        bfr[nt][kt] = *reinterpret_cast<const bf16x8_t*>(&Bs[r * 64 + slot * 8]);
      }
    }
#pragma unroll
    for (int mt = 0; mt < 4; ++mt)
#pragma unroll
      for (int nt = 0; nt < 4; ++nt) {
        acc[mt][nt] = __builtin_amdgcn_mfma_f32_16x16x32_bf16(
            af[mt][0], bfr[nt][0], acc[mt][nt], 0, 0, 0);
        acc[mt][nt] = __builtin_amdgcn_mfma_f32_16x16x32_bf16(
            af[mt][1], bfr[nt][1], acc[mt][nt], 0, 0, 0);
      }
  }

#pragma unroll
  for (int mt = 0; mt < 4; ++mt)
#pragma unroll
    for (int i = 0; i < 4; ++i) {
      const size_t rowg = (size_t)(bm + wm + mt * 16 + quad * 4 + i);
#pragma unroll
      for (int nt = 0; nt < 4; ++nt) {
        float v = acc[mt][nt][i];
        if (isK) v = fmaxf(v, 0.f);
        C[rowg * 4096 + bnc + wn + nt * 16 + l15] = f2bfbits(v);
      }
    }
}

// ---------------------------------------------------------------------------
// Output MFMA GEMM: out[M,N] = A[M,K] @ Bt[N,K]^T + bias[N], fp32 out.
// 128(M) x 64(N) tile, BK=64 (R4-validated).
// ---------------------------------------------------------------------------
__global__ __launch_bounds__(256) void gemm_out_bf16(
    const unsigned short* __restrict__ A,   // [M][K] bf16
    const unsigned short* __restrict__ Bt,  // [N][K] bf16
    const float* __restrict__ bias,
    float* __restrict__ out, int M, int N, int K)
{
  __shared__ __align__(16) unsigned short As[128 * 64];  // 16 KB
  __shared__ __align__(16) unsigned short Bs[64 * 64];   //  8 KB

  int bxi, byi;
  swizzle_xy(bxi, byi);
  const int tid  = threadIdx.x;
  const int bm   = byi * 128;
  const int bn   = bxi * 64;
  const int lane = tid & 63;
  const int w    = tid >> 6;
  const int wm   = (w & 1) * 64;
  const int wn   = (w >> 1) * 32;
  const int quad = lane >> 4;
  const int l15  = lane & 15;

  f32x4_t acc[4][2];
#pragma unroll
  for (int mt = 0; mt < 4; ++mt)
#pragma unroll
    for (int nt = 0; nt < 2; ++nt) acc[mt][nt] = (f32x4_t){0.f, 0.f, 0.f, 0.f};

  int qa[4], ra[4], ca[4];
#pragma unroll
  for (int j = 0; j < 4; ++j) {
    qa[j] = tid + 256 * j;
    ra[j] = qa[j] >> 3;
    ca[j] = (qa[j] & 7) ^ (ra[j] & 7);
  }
  int qb[2], rb[2], cb[2];
#pragma unroll
  for (int j = 0; j < 2; ++j) {
    qb[j] = tid + 256 * j;
    rb[j] = qb[j] >> 3;
    cb[j] = (qb[j] & 7) ^ (rb[j] & 7);
  }

  for (int k0 = 0; k0 < K; k0 += 64) {
    __syncthreads();
#pragma unroll
    for (int j = 0; j < 4; ++j)
      load_lds16(&A[(size_t)(bm + ra[j]) * K + k0 + ca[j] * 8], &As[qa[j] * 8]);
#pragma unroll
    for (int j = 0; j < 2; ++j)
      load_lds16(&Bt[(size_t)(bn + rb[j]) * K + k0 + cb[j] * 8], &Bs[qb[j] * 8]);
    __syncthreads();

    bf16x8_t af[4][2], bfr[2][2];
#pragma unroll
    for (int mt = 0; mt < 4; ++mt) {
      const int r = wm + mt * 16 + l15;
#pragma unroll
      for (int kt = 0; kt < 2; ++kt) {
        const int slot = (kt * 4 + quad) ^ (r & 7);
        af[mt][kt] = *reinterpret_cast<const bf16x8_t*>(&As[r * 64 + slot * 8]);
      }
    }
#pragma unroll
    for (int nt = 0; nt < 2; ++nt) {
      const int r = wn + nt * 16 + l15;
#pragma unroll
      for (int kt = 0; kt < 2; ++kt) {
        const int slot = (kt * 4 + quad) ^ (r & 7);
        bfr[nt][kt] = *reinterpret_cast<const bf16x8_t*>(&Bs[r * 64 + slot * 8]);
      }
    }
#pragma unroll
    for (int mt = 0; mt < 4; ++mt)
#pragma unroll
      for (int nt = 0; nt < 2; ++nt) {
        acc[mt][nt] = __builtin_amdgcn_mfma_f32_16x16x32_bf16(
            af[mt][0], bfr[nt][0], acc[mt][nt], 0, 0, 0);
        acc[mt][nt] = __builtin_amdgcn_mfma_f32_16x16x32_bf16(
            af[mt][1], bfr[nt][1], acc[mt][nt], 0, 0, 0);
      }
  }

#pragma unroll
  for (int mt = 0; mt < 4; ++mt)
#pragma unroll
    for (int i = 0; i < 4; ++i) {
      const size_t rowg = (size_t)(bm + wm + mt * 16 + quad * 4 + i);
#pragma unroll
      for (int nt = 0; nt < 2; ++nt) {
        const int colg = bn + wn + nt * 16 + l15;
        out[rowg * N + colg] = acc[mt][nt][i] + bias[colg];
      }
    }
}

// ---------------------------------------------------------------------------
// ksum[t][d] = sum_i K[t][i*64+d].  One wave per token, 4 tokens/block.
// ---------------------------------------------------------------------------
__global__ __launch_bounds__(256) void ksum_kernel(
    const unsigned short* __restrict__ Kb, float* __restrict__ ks)
{
  const int t = blockIdx.x * 4 + (threadIdx.x >> 6);
  const int j = threadIdx.x & 63;
  const uint4* row = reinterpret_cast<const uint4*>(Kb + (size_t)t * INNER);
  float s[8] = {0.f, 0.f, 0.f, 0.f, 0.f, 0.f, 0.f, 0.f};
#pragma unroll
  for (int m = 0; m < 8; ++m) {
    const uint4 u = row[j + 64 * m];
    s[0] += __uint_as_float((u.x & 0xFFFFu) << 16);
    s[1] += __uint_as_float(u.x & 0xFFFF0000u);
    s[2] += __uint_as_float((u.y & 0xFFFFu) << 16);
    s[3] += __uint_as_float(u.y & 0xFFFF0000u);
    s[4] += __uint_as_float((u.z & 0xFFFFu) << 16);
    s[5] += __uint_as_float(u.z & 0xFFFF0000u);
    s[6] += __uint_as_float((u.w & 0xFFFFu) << 16);
    s[7] += __uint_as_float(u.w & 0xFFFF0000u);
  }
#pragma unroll
  for (int off = 8; off < 64; off <<= 1)
#pragma unroll
    for (int e = 0; e < 8; ++e) s[e] += __shfl_xor(s[e], off, 64);
  if (j < 8) {
    float4* dst = reinterpret_cast<float4*>(ks + t * 64 + j * 8);
    float4 lo, hi;
    lo.x = s[0]; lo.y = s[1]; lo.z = s[2]; lo.w = s[3];
    hi.x = s[4]; hi.y = s[5]; hi.z = s[6]; hi.w = s[7];
    dst[0] = lo; dst[1] = hi;
  }
}

// ---------------------------------------------------------------------------
// MFMA attention: one wave per token, 4 tokens/block, zero LDS (R3-verified).
// ---------------------------------------------------------------------------
__global__ __launch_bounds__(256) void attn_mfma(
    const unsigned short* __restrict__ Qb, const unsigned short* __restrict__ Vb,
    const float* __restrict__ ksum, unsigned short* __restrict__ Ab)
{
  const int t    = blockIdx.x * 4 + (threadIdx.x >> 6);
  const int lane = threadIdx.x & 63;
  const int l15  = lane & 15;
  const int quad = lane >> 4;
  const size_t base = (size_t)t * INNER;

  union VU { bf16x8_t v; unsigned short u[8]; };

  float ksv[2][8];
#pragma unroll
  for (int kt = 0; kt < 2; ++kt) {
    const float4* p = reinterpret_cast<const float4*>(ksum + t * 64 + kt * 32 + quad * 8);
    const float4 a = p[0], b = p[1];
    ksv[kt][0] = a.x; ksv[kt][1] = a.y; ksv[kt][2] = a.z; ksv[kt][3] = a.w;
    ksv[kt][4] = b.x; ksv[kt][5] = b.y; ksv[kt][6] = b.z; ksv[kt][7] = b.w;
  }

  bf16x8_t vs[4][2];
#pragma unroll
  for (int nt = 0; nt < 4; ++nt)
#pragma unroll
    for (int kt = 0; kt < 2; ++kt) {
      VU vr, vo;
      vr.v = *reinterpret_cast<const bf16x8_t*>(
          Vb + base + (size_t)(nt * 16 + l15) * 64 + kt * 32 + quad * 8);
#pragma unroll
      for (int j = 0; j < 8; ++j)
        vo.u[j] = f2bfbits(bfbits2f(vr.u[j]) * ksv[kt][j]);
      vs[nt][kt] = vo.v;
    }

  bf16x8_t qf[4][2];
  float qn[4] = {0.f, 0.f, 0.f, 0.f};
#pragma unroll
  for (int mt = 0; mt < 4; ++mt)
#pragma unroll
    for (int kt = 0; kt < 2; ++kt) {
      VU qr;
      qr.v = *reinterpret_cast<const bf16x8_t*>(
          Qb + base + (size_t)(mt * 16 + l15) * 64 + kt * 32 + quad * 8);
      qf[mt][kt] = qr.v;
#pragma unroll
      for (int j = 0; j < 8; ++j)
        qn[mt] += bfbits2f(qr.u[j]) * ksv[kt][j];
    }
#pragma unroll
  for (int mt = 0; mt < 4; ++mt) {
    qn[mt] += __shfl_xor(qn[mt], 16, 64);
    qn[mt] += __shfl_xor(qn[mt], 32, 64);
  }

  f32x4_t acc[4][4];
#pragma unroll
  for (int mt = 0; mt < 4; ++mt)
#pragma unroll
    for (int nt = 0; nt < 4; ++nt) acc[mt][nt] = (f32x4_t){0.f, 0.f, 0.f, 0.f};

#pragma unroll
  for (int mt = 0; mt < 4; ++mt)
#pragma unroll
    for (int nt = 0; nt < 4; ++nt) {
      acc[mt][nt] = __builtin_amdgcn_mfma_f32_16x16x32_bf16(
          qf[mt][0], vs[nt][0], acc[mt][nt], 0, 0, 0);
      acc[mt][nt] = __builtin_amdgcn_mfma_f32_16x16x32_bf16(
          qf[mt][1], vs[nt][1], acc[mt][nt], 0, 0, 0);
    }

#pragma unroll
  for (int mt = 0; mt < 4; ++mt)
#pragma unroll
    for (int i = 0; i < 4; ++i) {
      const float inv = 1.f / (__shfl(qn[mt], quad * 4 + i, 64) + EPS);
      const size_t roff = base + (size_t)(mt * 16 + quad * 4 + i) * 64;
#pragma unroll
      for (int nt = 0; nt < 4; ++nt)
        Ab[roff + nt * 16 + l15] = f2bfbits(acc[mt][nt][i] * inv);
    }
}

// ---------------------------------------------------------------------------
// Buffers (ws = 130 MB):
//  ws   @0      : K (transient) -> Q -> A (in place)
//  ws   @64MB   : V ; first 8MB reused for Wo^T after attn
//  ws   @128MB  : ksum (fp32 8192x64, 2MB)
//  d_out@0      : Xb (bf16 8192x1024, 16MB)       — dead before gemm_out writes
//  d_out@16MB   : WtKV (bf16 8192x1024, 16MB)     — then WqT (8MB)
// ---------------------------------------------------------------------------
extern "C" void kernel_launch(void* const* d_in, const int* in_sizes, int n_in,
                              void* d_out, int out_size, void* d_ws, size_t ws_size,
                              hipStream_t stream)
{
  const float* x  = (const float*)d_in[0];
  const float* Wq = (const float*)d_in[1];
  const float* Wk = (const float*)d_in[2];
  const float* Wv = (const float*)d_in[3];
  const float* Wo = (const float*)d_in[4];
  const float* bo = (const float*)d_in[5];
  float* out = (float*)d_out;

  uint8_t* ws = (uint8_t*)d_ws;
  const size_t HALF = (size_t)M_TOK * INNER * sizeof(bf16);  // 64 MB
  unsigned short* KQA = (unsigned short*)ws;            // K -> Q -> A
  unsigned short* Vb  = (unsigned short*)(ws + HALF);   // V ; then Wo^T
  float* ks           = (float*)(ws + 2 * HALF);

  unsigned short* Xb   = (unsigned short*)d_out;                           // 16 MB
  unsigned short* WtKV = (unsigned short*)((uint8_t*)d_out + (16u << 20)); // 16 MB
  unsigned short* WqT  = WtKV;   // reused after gemm_kv
  unsigned short* Wot  = Vb;     // Wo^T over dead V (after attn)

  const dim3 blk(256);

  castx_kernel<<<dim3(M_TOK * DIM / 4 / 256), blk, 0, stream>>>(
      x, Xb, M_TOK * DIM / 4);

  // Wk^T and Wv^T stacked -> WtKV [8192][1024]
  tcast_dual_kernel<<<dim3(INNER / 32, DIM / 32, 2), blk, 0, stream>>>(
      Wk, Wv, WtKV, DIM, INNER);

  gemm_kv<<<dim3(2 * INNER / 128, M_TOK / 128), blk, 0, stream>>>(
      Xb, WtKV, KQA, Vb, DIM);

  ksum_kernel<<<dim3(M_TOK / 4), blk, 0, stream>>>(KQA, ks);

  tcast_kernel<<<dim3(INNER / 32, DIM / 32), blk, 0, stream>>>(
      Wq, WqT, DIM, INNER);

  gemm_bf16<2><<<dim3(INNER / 128, M_TOK / 128), blk, 0, stream>>>(
      Xb, WqT, KQA, M_TOK, INNER, DIM);  // Q overwrites dead K

  attn_mfma<<<dim3(M_TOK / 4), blk, 0, stream>>>(KQA, Vb, ks, KQA);  // A in place

  tcast_kernel<<<dim3(DIM / 32, INNER / 32), blk, 0, stream>>>(
      Wo, Wot, INNER, DIM);  // over dead V

  gemm_out_bf16<<<dim3(DIM / 64, M_TOK / 128), blk, 0, stream>>>(
      KQA, Wot, bo, out, M_TOK, DIM, INNER);
}